// Round 4
// baseline (1697.139 us; speedup 1.0000x reference)
//
#include <hip/hip_runtime.h>
#include <hip/hip_bf16.h>

#define VV 50000
#define DD 256
#define HH 128
#define G4 512
#define BB 8
#define SS 512
#define TT 100
#define T1 101
#define GAMMA 1.0f
#define LOG2E 1.44269504f
#define CGB 224              // GEMM blocks
#define TPB 14               // vocab 16-tiles per GEMM block (224*14*16 = 50176)
#define NBLK (17+8+CGB)      // 0-7 AB, 8-15 CTX, 16 combine, 17-24 SC2, 25..248 GEMM

// ---- batched-barrier pipeline: KB decoder steps per device barrier ----
#define KB 25                // steps per barrier (TT % KB == 0)
#define NAB (TT/KB)          // AB-active iterations = 4
#define NIT (NAB+3)          // total iterations incl. 3 pipeline-drain lags = 7
// ring-buffer slot masks (windows of KB at lag spans {50,50,75,100,50} disjoint):
#define AT_M 63              // attn  depth 64
#define CX_M 63              // ctx   depth 64
#define HN_M 127             // hn    depth 128
#define CV_M 127             // covloss depth 128
#define PM_M 63              // pm/ps depth 64

// score k2-split: AB owns [0,A_K2), SC2 owns [A_K2,64)
#define A_K2 36
#define B_K2 (64-A_K2)
// tag dword offsets inside bar (bar[0..1024) zeroed by k_xd)
#define THN 640
#define TGA 768
#define TGB 896

__device__ inline float rcpf_(float x){
#if __has_builtin(__builtin_amdgcn_rcpf)
  return __builtin_amdgcn_rcpf(x);
#else
  return 1.0f/x;
#endif
}
__device__ inline float exp2f_(float x){
#if __has_builtin(__builtin_amdgcn_exp2f)
  return __builtin_amdgcn_exp2f(x);
#else
  return exp2f(x);
#endif
}
__device__ inline float log2f_(float x){
#if __has_builtin(__builtin_amdgcn_logf)
  return __builtin_amdgcn_logf(x);
#else
  return log2f(x);
#endif
}
__device__ inline float fexp(float x){ return exp2f_(x*LOG2E); }
__device__ inline float sigf(float x){ return rcpf_(1.f + exp2f_(-x*LOG2E)); }
__device__ inline float tanh_(float x){
  float e = exp2f_(x*(2.0f*LOG2E));
  return 1.0f - 2.0f*rcpf_(e+1.0f);
}
__device__ inline unsigned short f2bf(float x){
  unsigned u = __float_as_uint(x);
  return (unsigned short)((u + 0x7fffu + ((u>>16)&1u)) >> 16);
}
__device__ inline float bf2f(unsigned short s){ return __uint_as_float(((unsigned)s)<<16); }
__device__ inline float bfrnd(float x){
  return __uint_as_float((__float_as_uint(x)+0x8000u)&0xffff0000u);
}
__device__ inline unsigned pack2rq(float a, float b){
#if __has_builtin(__builtin_amdgcn_perm)
  unsigned ua = __float_as_uint(a) + 0x8000u;
  unsigned ub = __float_as_uint(b) + 0x8000u;
  return __builtin_amdgcn_perm(ub, ua, 0x07060302u);
#else
  unsigned ra = (__float_as_uint(a)+0x8000u)>>16;
  unsigned rb = (__float_as_uint(b)+0x8000u)>>16;
  return ra | (rb<<16);
#endif
}

typedef __attribute__((ext_vector_type(2))) _Float16 h2v;
typedef __attribute__((ext_vector_type(8))) short bfrag;
typedef __attribute__((ext_vector_type(4))) float cfrag;

__device__ inline unsigned packh2(float a, float b){
  unsigned short ha = __builtin_bit_cast(unsigned short, (_Float16)a);
  unsigned short hb = __builtin_bit_cast(unsigned short, (_Float16)b);
  return (unsigned)ha | ((unsigned)hb<<16);
}
__device__ inline float fdot2_(unsigned a, unsigned b, float c){
#if __has_builtin(__builtin_amdgcn_fdot2)
  return __builtin_amdgcn_fdot2(__builtin_bit_cast(h2v, a), __builtin_bit_cast(h2v, b), c, false);
#else
  h2v av = __builtin_bit_cast(h2v, a), bv = __builtin_bit_cast(h2v, b);
  return c + (float)av.x*(float)bv.x + (float)av.y*(float)bv.y;
#endif
}
__device__ inline float hlo(unsigned u){ return (float)__builtin_bit_cast(h2v, u).x; }
__device__ inline float hhi(unsigned u){ return (float)__builtin_bit_cast(h2v, u).y; }

// ---- publish/poll helpers (agent scope, gbar-style fence discipline) ----
__device__ inline void tag_pub(unsigned* tag, unsigned v){
  __threadfence();
  __hip_atomic_store(tag, v, __ATOMIC_RELEASE, __HIP_MEMORY_SCOPE_AGENT);
}
__device__ inline void tag_poll(unsigned* tag, unsigned v){
  while (__hip_atomic_load(tag, __ATOMIC_RELAXED, __HIP_MEMORY_SCOPE_AGENT) < v)
    __builtin_amdgcn_s_sleep(1);
  __threadfence();
}

// ------ hierarchical device-scope barrier: 8 padded group lines + root ------
__device__ inline void gbar(unsigned* bar){
  __syncthreads();
  if (threadIdx.x == 0){
    __threadfence();
    int g = blockIdx.x & 7;
    unsigned gsz = (unsigned)((NBLK + 7 - g) >> 3);
    unsigned gen = __hip_atomic_load(bar+576, __ATOMIC_RELAXED, __HIP_MEMORY_SCOPE_AGENT);
    unsigned old = __hip_atomic_fetch_add(bar+64*g, 1u, __ATOMIC_ACQ_REL, __HIP_MEMORY_SCOPE_AGENT);
    if (old == gsz-1u){
      __hip_atomic_store(bar+64*g, 0u, __ATOMIC_RELAXED, __HIP_MEMORY_SCOPE_AGENT);
      unsigned go = __hip_atomic_fetch_add(bar+512, 1u, __ATOMIC_ACQ_REL, __HIP_MEMORY_SCOPE_AGENT);
      if (go == 7u){
        __hip_atomic_store(bar+512, 0u, __ATOMIC_RELAXED, __HIP_MEMORY_SCOPE_AGENT);
        __hip_atomic_fetch_add(bar+576, 1u, __ATOMIC_RELEASE, __HIP_MEMORY_SCOPE_AGENT);
      } else {
        while (__hip_atomic_load(bar+576, __ATOMIC_RELAXED, __HIP_MEMORY_SCOPE_AGENT) == gen)
          __builtin_amdgcn_s_sleep(2);
      }
    } else {
      while (__hip_atomic_load(bar+576, __ATOMIC_RELAXED, __HIP_MEMORY_SCOPE_AGENT) == gen)
        __builtin_amdgcn_s_sleep(2);
    }
    __threadfence();
  }
  __syncthreads();
}

// ---------------- prep: small weight transposes/packs ----------------
__global__ void __launch_bounds__(256) k_prep_small(
    const float* Wih_f, const float* Wih_b, const float* Whh_f, const float* Whh_b,
    const float* W1, const float* Wdhh,
    float* WihT_f, float* WihT_b, unsigned* W2T_f, unsigned* W2T_b,
    float* W1aT, float* W1c, unsigned* W1h2, unsigned* Wdh2T){
  int i = blockIdx.x*256 + threadIdx.x;
  if (i < 131072){ int k = i>>9, j = i&511; WihT_f[i] = Wih_f[j*DD + k]; return; }
  i -= 131072;
  if (i < 131072){ int k = i>>9, j = i&511; WihT_b[i] = Wih_b[j*DD + k]; return; }
  i -= 131072;
  if (i < 32768){ int k2 = i>>9, j = i&511;
    W2T_f[i] = packh2(Whh_f[j*HH + 2*k2], Whh_f[j*HH + 2*k2+1]); return; }
  i -= 32768;
  if (i < 32768){ int k2 = i>>9, j = i&511;
    W2T_b[i] = packh2(Whh_b[j*HH + 2*k2], Whh_b[j*HH + 2*k2+1]); return; }
  i -= 32768;
  if (i < 32768){ int d = i>>7, k = i&127; W1aT[i] = W1[k*385 + d]; return; }
  i -= 32768;
  if (i < 128){ W1c[i] = W1[i*385 + 384]; return; }
  i -= 128;
  if (i < 8192){ int j2 = i>>7, col = i&127;
    W1h2[i] = packh2(W1[col*385 + 256 + 2*j2], W1[col*385 + 256 + 2*j2+1]); return; }
  i -= 8192;
  if (i < 32768){ int q = i>>9, jj = i&511;
    Wdh2T[i] = packh2(Wdhh[jj*HH + 2*q], Wdhh[jj*HH + 2*q+1]); return; }
}

// ---------------- Xd[t][b][j] = Wdih@x + bdih + bdhh ; also zero barrier -----
__global__ void __launch_bounds__(512) k_xd(const int* summary, const float* wv,
    const float* Wdih, const float* bdih, const float* bdhh,
    float* Xd, unsigned* bar){
  __shared__ float xsl[8][256];
  int t = blockIdx.x, tid = threadIdx.x;
  for (int f=tid; f<2048; f+=512){
    int b = f>>8, k = f&255;
    xsl[b][k] = wv[(size_t)summary[b*T1 + t]*DD + k];
  }
  if (blockIdx.x==0){ for (int f=tid; f<1024; f+=512) bar[f] = 0u; }
  __syncthreads();
  int jj = tid;
  float base = bdih[jj] + bdhh[jj];
  const float4* wr = (const float4*)(Wdih + (size_t)jj*DD);
  float acc[8];
  #pragma unroll
  for (int b=0;b<8;b++) acc[b]=0.f;
  for (int q=0;q<64;q++){
    float4 w = wr[q];
    #pragma unroll
    for (int b=0;b<8;b++)
      acc[b] += w.x*xsl[b][4*q] + w.y*xsl[b][4*q+1] + w.z*xsl[b][4*q+2] + w.w*xsl[b][4*q+3];
  }
  #pragma unroll
  for (int b=0;b<8;b++) Xd[((size_t)t*BB + b)*G4 + jj] = base + acc[b];
}

// ---------------- embedding gather + ridx ----------------
__global__ void k_embed(const int* text, const int* tlen, const float* wv,
                        float* emb, int* ridx){
  int blk = blockIdx.x;
  int b = blk>>9, s = blk&511;
  int tok = text[blk];
  const float4* src = (const float4*)(wv + (size_t)tok*DD);
  float4* dst = (float4*)(emb + (size_t)blk*DD);
  dst[threadIdx.x] = src[threadIdx.x];
  if (threadIdx.x==0){ int len = tlen[b]; ridx[blk] = (s < len) ? (len-1-s) : s; }
}

// ---------------- X = emb @ Wih^T + bih + bhh ----------------
__global__ void __launch_bounds__(256) k_xgemm(const float* emb, const int* ridx,
    const float* WihT, const float* bi, const float* bh, float* X, int rev){
  __shared__ float e_l[8][256];
  int tid = threadIdx.x;
  int g0 = blockIdx.x*8;
  int b = g0>>9;
  for (int r=0;r<8;r++){
    int s = (g0+r)&511;
    int src = rev ? ridx[b*SS + s] : s;
    e_l[r][tid] = emb[((size_t)(b*SS+src))*DD + tid];
  }
  __syncthreads();
  int j0 = tid, j1 = tid+256;
  float acc0[8], acc1[8];
  #pragma unroll
  for (int r=0;r<8;r++){ acc0[r]=0.f; acc1[r]=0.f; }
  for (int k=0;k<256;k++){
    float w0 = WihT[k*G4 + j0];
    float w1 = WihT[k*G4 + j1];
    #pragma unroll
    for (int r=0;r<8;r++){ float e = e_l[r][k]; acc0[r] += e*w0; acc1[r] += e*w1; }
  }
  float bb0 = bi[j0]+bh[j0], bb1 = bi[j1]+bh[j1];
  for (int r=0;r<8;r++){
    X[((size_t)(g0+r))*G4 + j0] = acc0[r] + bb0;
    X[((size_t)(g0+r))*G4 + j1] = acc1[r] + bb1;
  }
}

// ------ encoder: register Whh (f16), X preload x8, out buffered x8 ----------
__global__ void __launch_bounds__(512) k_encoder(const float* Xf, const float* Xb,
    const unsigned* W2Tf, const unsigned* W2Tb, const int* tlen,
    float* out_f, float* out_r, float* h0, float* c0){
  __shared__ float g_l[512];
  __shared__ __align__(16) unsigned h2_l[64];
  int tid = threadIdx.x;
  int b = blockIdx.x, dir = blockIdx.y;
  const float* X = dir ? Xb : Xf;
  const unsigned* WT = dir ? W2Tb : W2Tf;
  float* out = dir ? out_r : out_f;
  unsigned w[64];
  #pragma unroll
  for (int k2=0;k2<64;k2++) w[k2] = WT[k2*G4 + tid];
  if (tid < 64) h2_l[tid] = 0u;
  float creg = 0.f, hreg = 0.f;
  int len = tlen[b];
  __syncthreads();
  for (int t0=0;t0<len;t0+=8){
    float x8[8];
    #pragma unroll
    for (int i=0;i<8;i++) x8[i] = X[(size_t)(b*SS+t0+i)*G4 + tid];
    float out8[8];
    #pragma unroll
    for (int i=0;i<8;i++){
      int t = t0+i;
      if (t >= len) break;
      float a0 = x8[i], a1 = 0.f, a2 = 0.f, a3 = 0.f;
      const uint4* h4 = (const uint4*)h2_l;
      #pragma unroll
      for (int q=0;q<16;q++){
        uint4 hv = h4[q];
        a0 = fdot2_(w[4*q+0], hv.x, a0);
        a1 = fdot2_(w[4*q+1], hv.y, a1);
        a2 = fdot2_(w[4*q+2], hv.z, a2);
        a3 = fdot2_(w[4*q+3], hv.w, a3);
      }
      g_l[tid] = (a0+a1)+(a2+a3);
      __syncthreads();
      if (tid < 128){
        float ii = sigf(g_l[tid]);
        float ff = sigf(g_l[128+tid]);
        float gg = tanh_(g_l[256+tid]);
        float oo = sigf(g_l[384+tid]);
        creg = ff*creg + ii*gg;
        float hn = oo*tanh_(creg);
        out8[i] = hn;
        hreg = hn;
        ((_Float16*)h2_l)[tid] = (_Float16)hn;
      }
      __syncthreads();
    }
    if (tid < 128){
      int nend = (len - t0 < 8) ? (len - t0) : 8;
      #pragma unroll 8
      for (int i=0;i<nend;i++) out[((size_t)(b*SS+t0+i))*HH + tid] = out8[i];
    }
  }
  if (dir==0 && tid<128){ h0[b*HH+tid]=hreg; c0[b*HH+tid]=creg; }
  for (int f = tid; f < (SS-len)*HH; f += 512){
    int s = len + (f>>7), j = f&127;
    out[((size_t)(b*SS+s))*HH + j] = 0.f;
  }
}

// ------- post-encoder: ts_h (f16 pairs over s) + TS1Th (f16 pairs over k) ----
__global__ void __launch_bounds__(256) k_post(const float* out_f, const float* out_r,
    const int* ridx, const float* W1aT, unsigned* ts_h, unsigned* TS1Th){
  __shared__ float ts_l[128*33 + 64];
  int tid = threadIdx.x;
  int b = blockIdx.x, chunk = blockIdx.y;
  int s0 = chunk*32;
  for (int it=0; it<32; ++it){
    int s = s0 + it;
    int d = tid;
    float v;
    if (d < 128) v = out_f[((size_t)(b*SS+s))*HH + d];
    else        v = out_r[((size_t)(b*SS + ridx[b*SS+s]))*HH + (d-128)];
    ts_l[it*256 + d] = v;
  }
  __syncthreads();
  for (int f=tid; f<16*256; f+=256){
    int it2 = f>>8, d = f&255;
    unsigned p = packh2(ts_l[(2*it2)*256 + d], ts_l[(2*it2+1)*256 + d]);
    ts_h[((((size_t)b*2 + (s0>>8))*128) + (((s0&255)>>1) + it2))*256 + d] = p;
  }
  int k = tid & 127, half = tid >> 7;
  float acc[16];
  #pragma unroll
  for (int i=0;i<16;i++) acc[i]=0.f;
  for (int d=0;d<256;d++){
    float w = W1aT[d*128 + k];
    #pragma unroll
    for (int i=0;i<16;i++) acc[i] += ts_l[(half*16+i)*256 + d]*w;
  }
  __syncthreads();
  #pragma unroll
  for (int i=0;i<16;i++) ts_l[k*33 + half*16 + i] = acc[i];
  __syncthreads();
  for (int f=tid; f<64*32; f+=256){
    int k2 = f>>5, sl = f&31;
    unsigned p = packh2(ts_l[(2*k2)*33 + sl], ts_l[(2*k2+1)*33 + sl]);
    TS1Th[((size_t)b*64 + k2)*512 + (s0 + sl)] = p;
  }
}

// ---------------- persistent decoder ----------------
struct PArgs {
  const int* summary; const int* slen;
  const float* Xd; const unsigned* TS1Th; const unsigned* ts_h;
  const unsigned* W1h2g; const float* W1c; const float* W2; const float* b1;
  const unsigned* Wdh2T; const float* Wl; const float* bl;
  const float* h0; const float* c0;
  float* hn; float* ctx; float* attn; float* covloss;
  float* pm; float* ps; unsigned* bar; float* out;
  unsigned* hnG; float* scA; float* scB;
};

struct __align__(16) LdsAB {
  unsigned W1h2[8192];          // 32768 B
  float gates[512];
  float hnl[128], hml[128];
  unsigned hn2[64], hm2[64];    // 16B-aligned
  float4 uhwc[64];              // {uh0, uh1, wc0, wc1}
  float2 w2p[64];               // {w20, w21}
  float wredB[8], wredC[8];
};
struct LdsCG { unsigned short xs[16*392]; float rm[64], rs[64]; };
struct LdsCTX { float at[512]; float part[512]; };
struct LdsCB { float tgt[64*BB]; float red[8]; float loss; };
union LdsU { LdsAB ab; LdsCG cg; LdsCTX cx; LdsCB cb; };

__global__ void __launch_bounds__(512,2) k_decode(PArgs a){
  __shared__ LdsU L;
  int bid = blockIdx.x, tid = threadIdx.x;

  if (bid < 8){
    // ========== AB: cell + gates + uh + score k2<A_K2 + softmax ==========
    int b = bid;
    int slenb = a.slen[b];
    float b1r = (tid < 2*A_K2) ? a.b1[tid] : 0.f;
    if (tid < 64){
      L.ab.uhwc[tid] = make_float4(0.f, 0.f, a.W1c[2*tid], a.W1c[2*tid+1]);
      L.ab.w2p[tid]  = make_float2(a.W2[2*tid], a.W2[2*tid+1]);
    }
    for (int f=tid; f<8192; f+=512) L.ab.W1h2[f] = a.W1h2g[f];
    unsigned ts2[A_K2];
    #pragma unroll
    for (int k2=0;k2<A_K2;k2++) ts2[k2] = a.TS1Th[((size_t)b*64 + k2)*512 + tid];
    unsigned wdh[64];
    #pragma unroll
    for (int q=0;q<64;q++) wdh[q] = a.Wdh2T[q*512 + tid];
    float creg = 0.f, hmreg = 0.f;
    if (tid < 128){
      creg  = a.c0[b*HH+tid];
      hmreg = a.h0[b*HH+tid];
      L.ab.hml[tid] = hmreg;
    }
    float cv = 0.f;
    __syncthreads();
    if (tid < 64) L.ab.hm2[tid] = packh2(L.ab.hml[2*tid], L.ab.hml[2*tid+1]);
    __syncthreads();
    {
      const uint4* h4 = (const uint4*)L.ab.hm2;
      float g0 = a.Xd[(size_t)0*BB*G4 + b*G4 + tid], g1 = 0.f, g2 = 0.f, g3 = 0.f;
      #pragma unroll
      for (int q=0;q<16;q++){
        uint4 hv = h4[q];
        g0 = fdot2_(wdh[4*q+0], hv.x, g0);
        g1 = fdot2_(wdh[4*q+1], hv.y, g1);
        g2 = fdot2_(wdh[4*q+2], hv.z, g2);
        g3 = fdot2_(wdh[4*q+3], hv.w, g3);
      }
      L.ab.gates[tid] = (g0+g1)+(g2+g3);
    }
    __syncthreads();

    for (int it=0; it<NIT; ++it){
      if (it < NAB){
        #pragma unroll 1
        for (int j=0;j<KB;j++){
          int t = KB*it + j;
          if (j) __syncthreads();
          if (t >= TT) break;
          int tn = (t+1 < TT) ? t+1 : 0;
          float xdn = a.Xd[(size_t)tn*BB*G4 + b*G4 + tid];   // prefetch
          bool valid = (slenb > t+1);
          if (tid < 128){
            float gi = L.ab.gates[tid];
            float gf = L.ab.gates[128+tid];
            float gg = L.ab.gates[256+tid];
            float go = L.ab.gates[384+tid];
            float ii = sigf(gi), ff = sigf(gf), g2 = tanh_(gg), oo = sigf(go);
            float cn = ff*creg + ii*g2;
            float hv = oo*tanh_(cn);
            if (valid) creg = cn;
            hmreg = valid ? hv : hmreg;
            L.ab.hnl[tid] = hv;
            L.ab.hml[tid] = hmreg;
            a.hn[((size_t)(t&HN_M)*BB + b)*HH + tid] = hv;
          }
          __syncthreads();                 // S1: hnl/hml visible
          if (tid < 64){
            unsigned pn = packh2(L.ab.hnl[2*tid], L.ab.hnl[2*tid+1]);
            L.ab.hn2[tid] = pn;
            a.hnG[((size_t)b*2 + (t&1))*64 + tid] = pn;     // publish hn half
            L.ab.hm2[tid] = packh2(L.ab.hml[2*tid], L.ab.hml[2*tid+1]);
          }
          __syncthreads();                 // S2: hn2/hm2 + hnG stores done
          if (tid == 504) tag_pub(a.bar + THN + 16*b, (unsigned)(t+1));
          if (tid < 2*A_K2){
            const uint4* n4 = (const uint4*)L.ab.hn2;
            float u0 = b1r, u1 = 0.f, u2 = 0.f, u3 = 0.f;
            #pragma unroll
            for (int q=0;q<16;q++){
              uint4 nv = n4[q];
              u0 = fdot2_(L.ab.W1h2[(4*q+0)*128+tid], nv.x, u0);
              u1 = fdot2_(L.ab.W1h2[(4*q+1)*128+tid], nv.y, u1);
              u2 = fdot2_(L.ab.W1h2[(4*q+2)*128+tid], nv.z, u2);
              u3 = fdot2_(L.ab.W1h2[(4*q+3)*128+tid], nv.w, u3);
            }
            ((float*)L.ab.uhwc)[(tid>>1)*4 + (tid&1)] = (u0+u1)+(u2+u3);
          }
          __syncthreads();                 // S3: uh (A half) visible
          float sc0 = 0.f, sc1 = 0.f;
          #pragma unroll
          for (int k2=0;k2<A_K2;k2++){
            unsigned tp = ts2[k2];
            float4 uw  = L.ab.uhwc[k2];
            float2 w2v = L.ab.w2p[k2];
            float p0 = hlo(tp) + uw.x + cv*uw.z;
            float p1 = hhi(tp) + uw.y + cv*uw.w;
            sc0 += tanh_(p0)*w2v.x;
            sc1 += tanh_(p1)*w2v.y;
          }
          float scA = sc0 + sc1;
          a.scA[((size_t)b*2 + (t&1))*512 + tid] = scA;     // publish A partial
          __syncthreads();                 // S_pub: all scA stores done
          if (tid == 504) tag_pub(a.bar + TGA + 16*b, (unsigned)(t+1));
          if (tid == 0)   tag_poll(a.bar + TGB + 16*b, (unsigned)(t+1));
          __syncthreads();                 // S_rdy: scB visible
          float sc = scA + a.scB[((size_t)b*2 + (t&1))*512 + tid];
          // fused softmax (|sc| bounded; skip max)
          float e = fexp(sc);
          int wid = tid>>6;
          float es = e;
          #pragma unroll
          for (int off=32;off>=1;off>>=1) es += __shfl_xor(es, off, 64);
          if ((tid&63)==0) L.ab.wredB[wid] = es;
          __syncthreads();                 // S4
          float ssum = 0.f;
          #pragma unroll
          for (int w8=0;w8<8;w8++) ssum += L.ab.wredB[w8];
          float at = e * rcpf_(ssum);
          a.attn[((size_t)(t&AT_M)*BB + b)*SS + tid] = at;
          float cl = fminf(cv, at);
          #pragma unroll
          for (int off=32;off>=1;off>>=1) cl += __shfl_xor(cl, off, 64);
          if ((tid&63)==0) L.ab.wredC[wid] = cl;
          __syncthreads();                 // S5
          if (tid==0){
            float cvs = 0.f;
            #pragma unroll
            for (int w8=0;w8<8;w8++) cvs += L.ab.wredC[w8];
            a.covloss[(t&CV_M)*BB + b] = cvs;
          }
          if (valid) cv += at;
          if (t+1 < TT){
            const uint4* h4 = (const uint4*)L.ab.hm2;
            float g0 = xdn, g1 = 0.f, g2 = 0.f, g3 = 0.f;
            #pragma unroll
            for (int q=0;q<16;q++){
              uint4 hv = h4[q];
              g0 = fdot2_(wdh[4*q+0], hv.x, g0);
              g1 = fdot2_(wdh[4*q+1], hv.y, g1);
              g2 = fdot2_(wdh[4*q+2], hv.z, g2);
              g3 = fdot2_(wdh[4*q+3], hv.w, g3);
            }
            __syncthreads();               // S6: gates readers done
            L.ab.gates[tid] = (g0+g1)+(g2+g3);
          }
        }
      }
      gbar(a.bar);
    }
  } else if (bid < 16){
    // ================= CTX: context = attn @ ts (lag 1 iteration) ===========
    int b = bid-8;
    int d = tid & 255, half = tid >> 8;
    unsigned tsr[128];
    #pragma unroll
    for (int s2=0;s2<128;s2++)
      tsr[s2] = a.ts_h[((((size_t)b*2 + half)*128) + s2)*256 + d];
    for (int it=0; it<NIT; ++it){
      if (it >= 1 && it <= NAB){
        #pragma unroll 1
        for (int j=0;j<KB;j++){
          int s = KB*(it-1) + j;
          if (s >= TT) break;
          L.cx.at[tid] = a.attn[((size_t)(s&AT_M)*BB + b)*SS + tid];
          __syncthreads();
          float acc = 0.f;
          const float* ap = L.cx.at + half*256;
          #pragma unroll
          for (int s2=0;s2<128;s2++){
            float2 av = *(const float2*)&ap[2*s2];
            unsigned tp = tsr[s2];
            acc += hlo(tp)*av.x + hhi(tp)*av.y;
          }
          L.cx.part[tid] = acc;
          __syncthreads();
          if (tid < 256)
            a.ctx[((size_t)(s&CX_M)*BB + b)*256 + tid] = L.cx.part[tid] + L.cx.part[256+tid];
        }
      }
      gbar(a.bar);
    }
  } else if (bid == 16){
    // ========= CB: target logit (lag 2 iters) + LSE/loss (lag 3 iters) ======
    int b = tid >> 6, l = tid & 63;
    int slenb = a.slen[b];
    if (tid == 0) L.cb.loss = 0.f;
    __syncthreads();
    for (int it=0; it<NIT; ++it){
      #pragma unroll 1
      for (int j=0;j<KB;j++){
        int ts = KB*(it-2) + j;
        if (ts >= 0 && ts < TT){
          int tp = a.summary[b*T1 + ts+1];
          float acc = 0.f;
          #pragma unroll
          for (int i=0;i<6;i++){
            int k = l + 64*i;
            float x = (k < 256) ? a.ctx[((size_t)(ts&CX_M)*BB + b)*256 + k]
                                : a.hn[((size_t)(ts&HN_M)*BB + b)*HH + (k-256)];
            float w = a.Wl[(size_t)tp*384 + k];
            acc += bf2f(f2bf(x)) * bfrnd(w);
          }
          #pragma unroll
          for (int off=32;off>=1;off>>=1) acc += __shfl_xor(acc, off, 64);
          if (l==0) L.cb.tgt[(ts&63)*BB + b] = acc + a.bl[tp];
        }
        int cs = KB*(it-3) + j;
        if (cs >= 0 && cs < TT){
          int slot = cs&PM_M;
          const float* pmp = a.pm + (size_t)slot*BB*CGB + b*CGB;
          const float* psp = a.ps + (size_t)slot*BB*CGB + b*CGB;
          float m = -1e30f;
          for (int jb=l; jb<CGB; jb+=64) m = fmaxf(m, pmp[jb]);
          #pragma unroll
          for (int off=32;off>=1;off>>=1) m = fmaxf(m, __shfl_xor(m, off, 64));
          float s = 0.f;
          for (int jb=l; jb<CGB; jb+=64) s += psp[jb]*fexp(pmp[jb]-m);
          #pragma unroll
          for (int off=32;off>=1;off>>=1) s += __shfl_xor(s, off, 64);
          __syncthreads();
          if (l==0){
            float lse = m + log2f_(s)*0.6931472f;
            bool val = slenb > cs+1;
            L.cb.red[b] = val ? (lse - L.cb.tgt[(cs&63)*BB+b] + GAMMA*a.covloss[(cs&CV_M)*BB+b]) : 0.f;
          }
          __syncthreads();
          if (tid==0){
            float sum = 0.f;
            #pragma unroll
            for (int b2=0;b2<BB;b2++) sum += L.cb.red[b2];
            L.cb.loss += sum;
          }
        }
      }
      if (it==NIT-1 && tid==0) a.out[0] = L.cb.loss*(1.0f/TT);
      gbar(a.bar);
    }
  } else if (bid < 25){
    // ========== SC2: score k2 in [A_K2,64) — partner of AB block b ==========
    int b = bid-17;
    int slenb = a.slen[b];
    float b1r2 = (tid < 2*B_K2) ? a.b1[2*A_K2 + tid] : 0.f;
    if (tid < 64){
      L.ab.uhwc[tid] = make_float4(0.f, 0.f, a.W1c[2*tid], a.W1c[2*tid+1]);
      L.ab.w2p[tid]  = make_float2(a.W2[2*tid], a.W2[2*tid+1]);
    }
    for (int f=tid; f<8192; f+=512) L.ab.W1h2[f] = a.W1h2g[f];
    unsigned ts2b[B_K2];
    #pragma unroll
    for (int i=0;i<B_K2;i++) ts2b[i] = a.TS1Th[((size_t)b*64 + (A_K2+i))*512 + tid];
    float cv = 0.f;
    __syncthreads();
    for (int it=0; it<NIT; ++it){
      if (it < NAB){
        #pragma unroll 1
        for (int j=0;j<KB;j++){
          int t = KB*it + j;
          if (t >= TT) break;
          if (tid == 0) tag_poll(a.bar + THN + 16*b, (unsigned)(t+1));
          __syncthreads();                 // hn ready
          if (tid < 64) L.ab.hn2[tid] = a.hnG[((size_t)b*2 + (t&1))*64 + tid];
          __syncthreads();
          if (tid < 2*B_K2){
            int col = 2*A_K2 + tid;
            const uint4* n4 = (const uint4*)L.ab.hn2;
            float u0 = b1r2, u1 = 0.f, u2 = 0.f, u3 = 0.f;
            #pragma unroll
            for (int q=0;q<16;q++){
              uint4 nv = n4[q];
              u0 = fdot2_(L.ab.W1h2[(4*q+0)*128+col], nv.x, u0);
              u1 = fdot2_(L.ab.W1h2[(4*q+1)*128+col], nv.y, u1);
              u2 = fdot2_(L.ab.W1h2[(4*q+2)*128+col], nv.z, u2);
              u3 = fdot2_(L.ab.W1h2[(4*q+3)*128+col], nv.w, u3);
            }
            ((float*)L.ab.uhwc)[(col>>1)*4 + (col&1)] = (u0+u1)+(u2+u3);
          }
          __syncthreads();                 // uh (B half) visible
          float sc0 = 0.f, sc1 = 0.f;
          #pragma unroll
          for (int i=0;i<B_K2;i++){
            int k2 = A_K2 + i;
            unsigned tp = ts2b[i];
            float4 uw  = L.ab.uhwc[k2];
            float2 w2v = L.ab.w2p[k2];
            float p0 = hlo(tp) + uw.x + cv*uw.z;
            float p1 = hhi(tp) + uw.y + cv*uw.w;
            sc0 += tanh_(p0)*w2v.x;
            sc1 += tanh_(p1)*w2v.y;
          }
          float scB = sc0 + sc1;
          a.scB[((size_t)b*2 + (t&1))*512 + tid] = scB;     // publish B partial
          __syncthreads();
          if (tid == 504) tag_pub(a.bar + TGB + 16*b, (unsigned)(t+1));
          if (tid == 0)   tag_poll(a.bar + TGA + 16*b, (unsigned)(t+1));
          __syncthreads();                 // scA visible
          float sc = a.scA[((size_t)b*2 + (t&1))*512 + tid] + scB;
          float e = fexp(sc);
          int wid = tid>>6;
          float es = e;
          #pragma unroll
          for (int off=32;off>=1;off>>=1) es += __shfl_xor(es, off, 64);
          if ((tid&63)==0) L.ab.wredB[wid] = es;
          __syncthreads();
          float ssum = 0.f;
          #pragma unroll
          for (int w8=0;w8<8;w8++) ssum += L.ab.wredB[w8];
          float at = e * rcpf_(ssum);
          bool valid = (slenb > t+1);
          if (valid) cv += at;
          __syncthreads();                 // wredB reuse guard for next j
        }
      }
      gbar(a.bar);
    }
  } else {
    // ====== CG: vocab MFMA GEMM, Wl in registers (lag 2 iterations) =========
    int cb = bid-25;
    int lane = tid & 63, wid = tid >> 6;
    int quad = lane >> 4, col = lane & 15;
    uint4 wreg[24];
    float biasv[2];
    bool nOK[2];
    #pragma unroll
    for (int lt=0; lt<2; lt++){
      int lti = lt*8 + wid;
      bool gv = (lti < TPB);
      int g = cb*TPB + (gv ? lti : 0);
      int n = g*16 + col;
      int nc = (n < VV) ? n : (VV-1);
      const float* wr0 = a.Wl + (size_t)nc*384 + quad*8;
      #pragma unroll
      for (int ks=0; ks<12; ks++){
        float4 w0 = *((const float4*)(wr0 + ks*32));
        float4 w1 = *((const float4*)(wr0 + ks*32 + 4));
        wreg[lt*12+ks] = make_uint4(pack2rq(w0.x,w0.y), pack2rq(w0.z,w0.w),
                                    pack2rq(w1.x,w1.y), pack2rq(w1.z,w1.w));
      }
      nOK[lt] = gv && (n < VV);
      biasv[lt] = nOK[lt] ? a.bl[n] : 0.f;
    }
    for (int it=0; it<NIT; ++it){
      if (it >= 2 && it <= NAB+1){
        #pragma unroll 1
        for (int j=0;j<KB;j++){
          int s = KB*(it-2) + j;
          if (s >= TT) break;
          for (int f=tid; f<16*384; f+=512){
            int m2 = f/384, k = f - m2*384;
            float v = 0.f;
            if (m2 < 8) v = (k < 256) ? a.ctx[((size_t)(s&CX_M)*BB + m2)*256 + k]
                                      : a.hn[((size_t)(s&HN_M)*BB + m2)*HH + (k-256)];
            L.cg.xs[m2*392 + k] = f2bf(v);
          }
          __syncthreads();
          const unsigned short* ap = L.cg.xs + col*392 + quad*8;
          float mr[4], sr[4];
          #pragma unroll
          for (int r=0;r<4;r++){ mr[r] = -1e30f; sr[r] = 0.f; }
          #pragma unroll
          for (int lt=0; lt<2; lt++){
            cfrag acc; acc.x=0.f; acc.y=0.f; acc.z=0.f; acc.w=0.f;
            #pragma unroll
            for (int ks=0; ks<12; ks++){
              bfrag af = *((const bfrag*)(ap + ks*32));
              bfrag bf = __builtin_bit_cast(bfrag, wreg[lt*12+ks]);
              acc = __builtin_amdgcn_mfma_f32_16x16x32_bf16(af, bf, acc, 0,0,0);
            }
            #pragma unroll
            for (int r=0;r<4;r++){
              int mrow = quad*4 + r;
              float v = (mrow < 8 && nOK[lt]) ? (acc[r]+biasv[lt]) : -1e30f;
              float nm = fmaxf(mr[r], v);
              float ev = (v <= -1e29f) ? 0.f : fexp(v-nm);
              sr[r] = sr[r]*fexp(mr[r]-nm) + ev;
              mr[r] = nm;
            }
          }
          #pragma unroll
          for (int off=1; off<16; off<<=1){
            #pragma unroll
            for (int r=0;r<4;r++){
              float m2 = __shfl_xor(mr[r], off, 64);
              float s2 = __shfl_xor(sr[r], off, 64);
              float nm = fmaxf(mr[r], m2);
              sr[r] = sr[r]*fexp(mr[r]-nm) + s2*fexp(m2-nm);
              mr[r] = nm;
            }
          }
          if (col==0 && quad<2){
            #pragma unroll
            for (int r=0;r<4;r++){
              L.cg.rm[wid*8 + quad*4 + r] = mr[r];
              L.cg.rs[wid*8 + quad*4 + r] = sr[r];
            }
          }
          __syncthreads();
          if (tid < 8){
            float M = -1e30f, S = 0.f;
            #pragma unroll
            for (int w8=0; w8<8; w8++){
              float m2 = L.cg.rm[w8*8+tid], s2 = L.cg.rs[w8*8+tid];
              float nm = fmaxf(M, m2);
              S = S*fexp(M-nm) + s2*fexp(m2-nm);
              M = nm;
            }
            a.pm[(size_t)(s&PM_M)*BB*CGB + tid*CGB + cb] = M;
            a.ps[(size_t)(s&PM_M)*BB*CGB + tid*CGB + cb] = S;
          }
        }
      }
      gbar(a.bar);
    }
  }
}

// ---------------- host ----------------
extern "C" void kernel_launch(void* const* d_in, const int* in_sizes, int n_in,
                              void* d_out, int out_size, void* d_ws, size_t ws_size,
                              hipStream_t stream){
  const int* text      = (const int*)d_in[0];
  const int* tlen      = (const int*)d_in[1];
  const int* summary   = (const int*)d_in[2];
  const int* slen      = (const int*)d_in[3];
  const float* wv      = (const float*)d_in[4];
  const float* Wih_f   = (const float*)d_in[5];
  const float* Whh_f   = (const float*)d_in[6];
  const float* bih_f   = (const float*)d_in[7];
  const float* bhh_f   = (const float*)d_in[8];
  const float* Wih_b   = (const float*)d_in[9];
  const float* Whh_b   = (const float*)d_in[10];
  const float* bih_b   = (const float*)d_in[11];
  const float* bhh_b   = (const float*)d_in[12];
  const float* Wdih    = (const float*)d_in[13];
  const float* Wdhh    = (const float*)d_in[14];
  const float* bdih    = (const float*)d_in[15];
  const float* bdhh    = (const float*)d_in[16];
  const float* W1      = (const float*)d_in[17];
  const float* b1      = (const float*)d_in[18];
  const float* W2      = (const float*)d_in[19];
  const float* Wl      = (const float*)d_in[21];
  const float* bl      = (const float*)d_in[22];

  char* ws = (char*)d_ws;
  size_t off = 0;
  auto alloc = [&](size_t n)->void*{
    off = (off + 255) & ~(size_t)255;
    void* p = ws + off; off += n; return p;
  };

  // ---- decode-persistent region ----
  unsigned* W1h2   = (unsigned*)alloc((size_t)8192*4);
  unsigned* Wdh2T  = (unsigned*)alloc((size_t)64*512*4);
  float*    Xd     = (float*)alloc((size_t)TT*BB*G4*4);
  unsigned* ts_h   = (unsigned*)alloc((size_t)BB*2*128*256*4);
  unsigned* TS1Th  = (unsigned*)alloc((size_t)BB*64*512*4);
  float* W1c       = (float*)alloc((size_t)128*4);
  float* h0        = (float*)alloc(BB*HH*4);
  float* c0        = (float*)alloc(BB*HH*4);
  float* hn        = (float*)alloc((size_t)(HN_M+1)*BB*HH*4);
  float* ctx       = (float*)alloc((size_t)(CX_M+1)*BB*256*4);
  float* attn      = (float*)alloc((size_t)(AT_M+1)*BB*SS*4);
  float* covloss   = (float*)alloc((size_t)(CV_M+1)*BB*4);
  float* pm        = (float*)alloc((size_t)(PM_M+1)*BB*CGB*4);
  float* ps        = (float*)alloc((size_t)(PM_M+1)*BB*CGB*4);
  unsigned* bar    = (unsigned*)alloc(4096);
  unsigned* hnG    = (unsigned*)alloc((size_t)BB*2*64*4);
  float* scA       = (float*)alloc((size_t)BB*2*512*4);
  float* scB       = (float*)alloc((size_t)BB*2*512*4);

  // ---- encoder-transient region ----
  float* emb     = (float*)alloc((size_t)BB*SS*DD*4);
  float* Xf      = (float*)alloc(((size_t)BB*SS*G4 + 8*G4)*4);
  float* Xb      = (float*)alloc(((size_t)BB*SS*G4 + 8*G4)*4);
  float* WihT_f  = (float*)alloc((size_t)256*512*4);
  float* WihT_b  = (float*)alloc((size_t)256*512*4);
  unsigned* W2T_f= (unsigned*)alloc((size_t)64*512*4);
  unsigned* W2T_b= (unsigned*)alloc((size_t)64*512*4);
  float* out_f   = (float*)alloc((size_t)BB*SS*HH*4);
  float* out_r   = (float*)alloc((size_t)BB*SS*HH*4);
  float* W1aT    = (float*)alloc((size_t)256*128*4);
  int*   ridx    = (int*)  alloc((size_t)BB*SS*4);

  k_prep_small<<<1569,256,0,stream>>>(Wih_f,Wih_b,Whh_f,Whh_b,W1,Wdhh,
                                      WihT_f,WihT_b,W2T_f,W2T_b,W1aT,W1c,W1h2,Wdh2T);
  k_xd<<<TT,512,0,stream>>>(summary, wv, Wdih, bdih, bdhh, Xd, bar);
  k_embed<<<BB*SS,64,0,stream>>>(text, tlen, wv, emb, ridx);
  k_xgemm<<<512,256,0,stream>>>(emb, ridx, WihT_f, bih_f, bhh_f, Xf, 0);
  k_xgemm<<<512,256,0,stream>>>(emb, ridx, WihT_b, bih_b, bhh_b, Xb, 1);
  k_encoder<<<dim3(8,2),512,0,stream>>>(Xf,Xb,W2T_f,W2T_b,tlen,out_f,out_r,h0,c0);
  k_post<<<dim3(8,16),256,0,stream>>>(out_f,out_r,ridx,W1aT,ts_h,TS1Th);

  PArgs a;
  a.summary=summary; a.slen=slen;
  a.Xd=Xd; a.TS1Th=TS1Th; a.ts_h=ts_h;
  a.W1h2g=W1h2; a.W1c=W1c; a.W2=W2; a.b1=b1;
  a.Wdh2T=Wdh2T; a.Wl=Wl; a.bl=bl;
  a.h0=h0; a.c0=c0;
  a.hn=hn; a.ctx=ctx; a.attn=attn; a.covloss=covloss;
  a.pm=pm; a.ps=ps; a.bar=bar; a.out=(float*)d_out;
  a.hnG=hnG; a.scA=scA; a.scB=scB;

  k_decode<<<NBLK,512,0,stream>>>(a);
}

// Round 5
// 1610.608 us; speedup vs baseline: 1.0537x; 1.0537x over previous
//
#include <hip/hip_runtime.h>
#include <hip/hip_bf16.h>

#define VV 50000
#define DD 256
#define HH 128
#define G4 512
#define BB 8
#define SS 512
#define TT 100
#define T1 101
#define GAMMA 1.0f
#define LOG2E 1.44269504f
#define CGB 224              // GEMM blocks
#define TPB 14               // vocab 16-tiles per GEMM block (224*14*16 = 50176)
#define NBLK (17+CGB)        // 0-7 AB, 8-15 CTX, 16 combine, 17..240 GEMM

// ---- batched-barrier pipeline: KB decoder steps per device barrier ----
#define KB 25                // steps per barrier (TT % KB == 0)
#define NAB (TT/KB)          // AB-active iterations = 4
#define NIT (NAB+3)          // total iterations incl. 3 pipeline-drain lags = 7
// ring-buffer slot masks (windows of KB at lag spans {50,50,75,100,50} disjoint):
#define AT_M 63              // attn  depth 64
#define CX_M 63              // ctx   depth 64
#define HN_M 127             // hn    depth 128
#define CV_M 127             // covloss depth 128
#define PM_M 63              // pm/ps depth 64

__device__ inline float rcpf_(float x){
#if __has_builtin(__builtin_amdgcn_rcpf)
  return __builtin_amdgcn_rcpf(x);
#else
  return 1.0f/x;
#endif
}
__device__ inline float exp2f_(float x){
#if __has_builtin(__builtin_amdgcn_exp2f)
  return __builtin_amdgcn_exp2f(x);
#else
  return exp2f(x);
#endif
}
__device__ inline float log2f_(float x){
#if __has_builtin(__builtin_amdgcn_logf)
  return __builtin_amdgcn_logf(x);
#else
  return log2f(x);
#endif
}
__device__ inline float fexp(float x){ return exp2f_(x*LOG2E); }
__device__ inline float sigf(float x){ return rcpf_(1.f + exp2f_(-x*LOG2E)); }
// tanh = 1 - 2/(e^2x+1): no clamp needed (inf -> 1, 0 -> -1), 5 ops, 2 trans
__device__ inline float tanh_(float x){
  float e = exp2f_(x*(2.0f*LOG2E));
  return 1.0f - 2.0f*rcpf_(e+1.0f);
}
__device__ inline unsigned short f2bf(float x){
  unsigned u = __float_as_uint(x);
  return (unsigned short)((u + 0x7fffu + ((u>>16)&1u)) >> 16);
}
__device__ inline float bf2f(unsigned short s){ return __uint_as_float(((unsigned)s)<<16); }
__device__ inline float bfrnd(float x){
  return __uint_as_float((__float_as_uint(x)+0x8000u)&0xffff0000u);
}
__device__ inline unsigned pack2rq(float a, float b){
#if __has_builtin(__builtin_amdgcn_perm)
  unsigned ua = __float_as_uint(a) + 0x8000u;
  unsigned ub = __float_as_uint(b) + 0x8000u;
  return __builtin_amdgcn_perm(ub, ua, 0x07060302u);
#else
  unsigned ra = (__float_as_uint(a)+0x8000u)>>16;
  unsigned rb = (__float_as_uint(b)+0x8000u)>>16;
  return ra | (rb<<16);
#endif
}

typedef __attribute__((ext_vector_type(2))) _Float16 h2v;
typedef __attribute__((ext_vector_type(8))) short bfrag;
typedef __attribute__((ext_vector_type(4))) float cfrag;

__device__ inline unsigned packh2(float a, float b){
  unsigned short ha = __builtin_bit_cast(unsigned short, (_Float16)a);
  unsigned short hb = __builtin_bit_cast(unsigned short, (_Float16)b);
  return (unsigned)ha | ((unsigned)hb<<16);
}
__device__ inline float fdot2_(unsigned a, unsigned b, float c){
#if __has_builtin(__builtin_amdgcn_fdot2)
  return __builtin_amdgcn_fdot2(__builtin_bit_cast(h2v, a), __builtin_bit_cast(h2v, b), c, false);
#else
  h2v av = __builtin_bit_cast(h2v, a), bv = __builtin_bit_cast(h2v, b);
  return c + (float)av.x*(float)bv.x + (float)av.y*(float)bv.y;
#endif
}
__device__ inline float hlo(unsigned u){ return (float)__builtin_bit_cast(h2v, u).x; }
__device__ inline float hhi(unsigned u){ return (float)__builtin_bit_cast(h2v, u).y; }

// ------ hierarchical device-scope barrier: 8 padded group lines + root ------
// bar layout (dwords): lcnt[g] @ 64*g (g=0..7), gcnt @ 512, gen @ 576
__device__ inline void gbar(unsigned* bar){
  __syncthreads();
  if (threadIdx.x == 0){
    __threadfence();
    int g = blockIdx.x & 7;
    unsigned gsz = (unsigned)((NBLK + 7 - g) >> 3);
    unsigned gen = __hip_atomic_load(bar+576, __ATOMIC_RELAXED, __HIP_MEMORY_SCOPE_AGENT);
    unsigned old = __hip_atomic_fetch_add(bar+64*g, 1u, __ATOMIC_ACQ_REL, __HIP_MEMORY_SCOPE_AGENT);
    if (old == gsz-1u){
      __hip_atomic_store(bar+64*g, 0u, __ATOMIC_RELAXED, __HIP_MEMORY_SCOPE_AGENT);
      unsigned go = __hip_atomic_fetch_add(bar+512, 1u, __ATOMIC_ACQ_REL, __HIP_MEMORY_SCOPE_AGENT);
      if (go == 7u){
        __hip_atomic_store(bar+512, 0u, __ATOMIC_RELAXED, __HIP_MEMORY_SCOPE_AGENT);
        __hip_atomic_fetch_add(bar+576, 1u, __ATOMIC_RELEASE, __HIP_MEMORY_SCOPE_AGENT);
      } else {
        while (__hip_atomic_load(bar+576, __ATOMIC_RELAXED, __HIP_MEMORY_SCOPE_AGENT) == gen)
          __builtin_amdgcn_s_sleep(2);
      }
    } else {
      while (__hip_atomic_load(bar+576, __ATOMIC_RELAXED, __HIP_MEMORY_SCOPE_AGENT) == gen)
        __builtin_amdgcn_s_sleep(2);
    }
    __threadfence();
  }
  __syncthreads();
}

// ---------------- prep: small weight transposes/packs ----------------
__global__ void __launch_bounds__(256) k_prep_small(
    const float* Wih_f, const float* Wih_b, const float* Whh_f, const float* Whh_b,
    const float* W1, const float* Wdhh,
    float* WihT_f, float* WihT_b, unsigned* W2T_f, unsigned* W2T_b,
    float* W1aT, float* W1c, unsigned* W1h2, unsigned* Wdh2T){
  int i = blockIdx.x*256 + threadIdx.x;
  if (i < 131072){ int k = i>>9, j = i&511; WihT_f[i] = Wih_f[j*DD + k]; return; }
  i -= 131072;
  if (i < 131072){ int k = i>>9, j = i&511; WihT_b[i] = Wih_b[j*DD + k]; return; }
  i -= 131072;
  if (i < 32768){ int k2 = i>>9, j = i&511;
    W2T_f[i] = packh2(Whh_f[j*HH + 2*k2], Whh_f[j*HH + 2*k2+1]); return; }
  i -= 32768;
  if (i < 32768){ int k2 = i>>9, j = i&511;
    W2T_b[i] = packh2(Whh_b[j*HH + 2*k2], Whh_b[j*HH + 2*k2+1]); return; }
  i -= 32768;
  if (i < 32768){ int d = i>>7, k = i&127; W1aT[i] = W1[k*385 + d]; return; }
  i -= 32768;
  if (i < 128){ W1c[i] = W1[i*385 + 384]; return; }
  i -= 128;
  if (i < 8192){ int j2 = i>>7, col = i&127;
    W1h2[i] = packh2(W1[col*385 + 256 + 2*j2], W1[col*385 + 256 + 2*j2+1]); return; }
  i -= 8192;
  if (i < 32768){ int q = i>>9, jj = i&511;
    Wdh2T[i] = packh2(Wdhh[jj*HH + 2*q], Wdhh[jj*HH + 2*q+1]); return; }
}

// ---------------- Xd[t][b][j] = Wdih@x + bdih + bdhh ; also zero barrier -----
__global__ void __launch_bounds__(512) k_xd(const int* summary, const float* wv,
    const float* Wdih, const float* bdih, const float* bdhh,
    float* Xd, unsigned* bar){
  __shared__ float xsl[8][256];
  int t = blockIdx.x, tid = threadIdx.x;
  for (int f=tid; f<2048; f+=512){
    int b = f>>8, k = f&255;
    xsl[b][k] = wv[(size_t)summary[b*T1 + t]*DD + k];
  }
  if (blockIdx.x==0){ for (int f=tid; f<1024; f+=512) bar[f] = 0u; }
  __syncthreads();
  int jj = tid;
  float base = bdih[jj] + bdhh[jj];
  const float4* wr = (const float4*)(Wdih + (size_t)jj*DD);
  float acc[8];
  #pragma unroll
  for (int b=0;b<8;b++) acc[b]=0.f;
  for (int q=0;q<64;q++){
    float4 w = wr[q];
    #pragma unroll
    for (int b=0;b<8;b++)
      acc[b] += w.x*xsl[b][4*q] + w.y*xsl[b][4*q+1] + w.z*xsl[b][4*q+2] + w.w*xsl[b][4*q+3];
  }
  #pragma unroll
  for (int b=0;b<8;b++) Xd[((size_t)t*BB + b)*G4 + jj] = base + acc[b];
}

// ---------------- embedding gather + ridx ----------------
__global__ void k_embed(const int* text, const int* tlen, const float* wv,
                        float* emb, int* ridx){
  int blk = blockIdx.x;
  int b = blk>>9, s = blk&511;
  int tok = text[blk];
  const float4* src = (const float4*)(wv + (size_t)tok*DD);
  float4* dst = (float4*)(emb + (size_t)blk*DD);
  dst[threadIdx.x] = src[threadIdx.x];
  if (threadIdx.x==0){ int len = tlen[b]; ridx[blk] = (s < len) ? (len-1-s) : s; }
}

// ---------------- X = emb @ Wih^T + bih + bhh ----------------
__global__ void __launch_bounds__(256) k_xgemm(const float* emb, const int* ridx,
    const float* WihT, const float* bi, const float* bh, float* X, int rev){
  __shared__ float e_l[8][256];
  int tid = threadIdx.x;
  int g0 = blockIdx.x*8;
  int b = g0>>9;
  for (int r=0;r<8;r++){
    int s = (g0+r)&511;
    int src = rev ? ridx[b*SS + s] : s;
    e_l[r][tid] = emb[((size_t)(b*SS+src))*DD + tid];
  }
  __syncthreads();
  int j0 = tid, j1 = tid+256;
  float acc0[8], acc1[8];
  #pragma unroll
  for (int r=0;r<8;r++){ acc0[r]=0.f; acc1[r]=0.f; }
  for (int k=0;k<256;k++){
    float w0 = WihT[k*G4 + j0];
    float w1 = WihT[k*G4 + j1];
    #pragma unroll
    for (int r=0;r<8;r++){ float e = e_l[r][k]; acc0[r] += e*w0; acc1[r] += e*w1; }
  }
  float bb0 = bi[j0]+bh[j0], bb1 = bi[j1]+bh[j1];
  for (int r=0;r<8;r++){
    X[((size_t)(g0+r))*G4 + j0] = acc0[r] + bb0;
    X[((size_t)(g0+r))*G4 + j1] = acc1[r] + bb1;
  }
}

// ------ encoder: register Whh (f16), X preload x8, out buffered x8 ----------
__global__ void __launch_bounds__(512) k_encoder(const float* Xf, const float* Xb,
    const unsigned* W2Tf, const unsigned* W2Tb, const int* tlen,
    float* out_f, float* out_r, float* h0, float* c0){
  __shared__ float g_l[512];
  __shared__ __align__(16) unsigned h2_l[64];
  int tid = threadIdx.x;
  int b = blockIdx.x, dir = blockIdx.y;
  const float* X = dir ? Xb : Xf;
  const unsigned* WT = dir ? W2Tb : W2Tf;
  float* out = dir ? out_r : out_f;
  unsigned w[64];
  #pragma unroll
  for (int k2=0;k2<64;k2++) w[k2] = WT[k2*G4 + tid];
  if (tid < 64) h2_l[tid] = 0u;
  float creg = 0.f, hreg = 0.f;
  int len = tlen[b];
  __syncthreads();
  for (int t0=0;t0<len;t0+=8){
    float x8[8];
    #pragma unroll
    for (int i=0;i<8;i++) x8[i] = X[(size_t)(b*SS+t0+i)*G4 + tid];
    float out8[8];
    #pragma unroll
    for (int i=0;i<8;i++){
      int t = t0+i;
      if (t >= len) break;
      float a0 = x8[i], a1 = 0.f, a2 = 0.f, a3 = 0.f;
      const uint4* h4 = (const uint4*)h2_l;
      #pragma unroll
      for (int q=0;q<16;q++){
        uint4 hv = h4[q];
        a0 = fdot2_(w[4*q+0], hv.x, a0);
        a1 = fdot2_(w[4*q+1], hv.y, a1);
        a2 = fdot2_(w[4*q+2], hv.z, a2);
        a3 = fdot2_(w[4*q+3], hv.w, a3);
      }
      g_l[tid] = (a0+a1)+(a2+a3);
      __syncthreads();
      if (tid < 128){
        float ii = sigf(g_l[tid]);
        float ff = sigf(g_l[128+tid]);
        float gg = tanh_(g_l[256+tid]);
        float oo = sigf(g_l[384+tid]);
        creg = ff*creg + ii*gg;
        float hn = oo*tanh_(creg);
        out8[i] = hn;
        hreg = hn;
        ((_Float16*)h2_l)[tid] = (_Float16)hn;
      }
      __syncthreads();
    }
    if (tid < 128){
      int nend = (len - t0 < 8) ? (len - t0) : 8;
      #pragma unroll 8
      for (int i=0;i<nend;i++) out[((size_t)(b*SS+t0+i))*HH + tid] = out8[i];
    }
  }
  if (dir==0 && tid<128){ h0[b*HH+tid]=hreg; c0[b*HH+tid]=creg; }
  for (int f = tid; f < (SS-len)*HH; f += 512){
    int s = len + (f>>7), j = f&127;
    out[((size_t)(b*SS+s))*HH + j] = 0.f;
  }
}

// ------- post-encoder: ts_h (f16 pairs over s) + TS1Th (f16 pairs over k) ----
__global__ void __launch_bounds__(256) k_post(const float* out_f, const float* out_r,
    const int* ridx, const float* W1aT, unsigned* ts_h, unsigned* TS1Th){
  __shared__ float ts_l[128*33 + 64];
  int tid = threadIdx.x;
  int b = blockIdx.x, chunk = blockIdx.y;
  int s0 = chunk*32;
  for (int it=0; it<32; ++it){
    int s = s0 + it;
    int d = tid;
    float v;
    if (d < 128) v = out_f[((size_t)(b*SS+s))*HH + d];
    else        v = out_r[((size_t)(b*SS + ridx[b*SS+s]))*HH + (d-128)];
    ts_l[it*256 + d] = v;
  }
  __syncthreads();
  for (int f=tid; f<16*256; f+=256){
    int it2 = f>>8, d = f&255;
    unsigned p = packh2(ts_l[(2*it2)*256 + d], ts_l[(2*it2+1)*256 + d]);
    ts_h[((((size_t)b*2 + (s0>>8))*128) + (((s0&255)>>1) + it2))*256 + d] = p;
  }
  int k = tid & 127, half = tid >> 7;
  float acc[16];
  #pragma unroll
  for (int i=0;i<16;i++) acc[i]=0.f;
  for (int d=0;d<256;d++){
    float w = W1aT[d*128 + k];
    #pragma unroll
    for (int i=0;i<16;i++) acc[i] += ts_l[(half*16+i)*256 + d]*w;
  }
  __syncthreads();
  #pragma unroll
  for (int i=0;i<16;i++) ts_l[k*33 + half*16 + i] = acc[i];
  __syncthreads();
  for (int f=tid; f<64*32; f+=256){
    int k2 = f>>5, sl = f&31;
    unsigned p = packh2(ts_l[(2*k2)*33 + sl], ts_l[(2*k2+1)*33 + sl]);
    TS1Th[((size_t)b*64 + k2)*512 + (s0 + sl)] = p;
  }
}

// ---------------- persistent decoder ----------------
struct PArgs {
  const int* summary; const int* slen;
  const float* Xd; const unsigned* TS1Th; const unsigned* ts_h;
  const unsigned* W1h2g; const float* W1c; const float* W2; const float* b1;
  const unsigned* Wdh2T; const float* Wl; const float* bl;
  const float* h0; const float* c0;
  float* hn; float* ctx; float* attn; float* covloss;
  float* pm; float* ps; unsigned* bar; float* out;
};

struct __align__(16) LdsAB {
  unsigned W1h2[8192];          // 32768 B
  float gates[512];
  float hnl[128], hml[128];
  unsigned hn2[64], hm2[64];    // 16B-aligned
  float4 uhwc[64];              // {uh0, uh1, wc0, wc1}
  float2 w2p[64];               // {w20, w21}
  float wredB[8], wredC[8];
};
struct LdsCG { unsigned short xs[16*392]; float rm[64], rs[64]; };
struct LdsCTX { float at[512]; float part[512]; };
struct LdsCB { float tgt[64*BB]; float red[8]; float loss; };
union LdsU { LdsAB ab; LdsCG cg; LdsCTX cx; LdsCB cb; };

__global__ void __launch_bounds__(512,1) k_decode(PArgs a){
  __shared__ LdsU L;
  int bid = blockIdx.x, tid = threadIdx.x;

  if (bid < 8){
    // ================= AB: cell + attention + gates (fused) =================
    int b = bid;
    int slenb = a.slen[b];
    float b1r = (tid < 128) ? a.b1[tid] : 0.f;
    if (tid < 64){
      L.ab.uhwc[tid] = make_float4(0.f, 0.f, a.W1c[2*tid], a.W1c[2*tid+1]);
      L.ab.w2p[tid]  = make_float2(a.W2[2*tid], a.W2[2*tid+1]);
    }
    for (int f=tid; f<8192; f+=512) L.ab.W1h2[f] = a.W1h2g[f];
    unsigned ts2[64];
    #pragma unroll
    for (int k2=0;k2<64;k2++) ts2[k2] = a.TS1Th[((size_t)b*64 + k2)*512 + tid];
    unsigned wdh[64];
    #pragma unroll
    for (int q=0;q<64;q++) wdh[q] = a.Wdh2T[q*512 + tid];
    float creg = 0.f, hmreg = 0.f;
    if (tid < 128){
      creg  = a.c0[b*HH+tid];
      hmreg = a.h0[b*HH+tid];
      L.ab.hml[tid] = hmreg;
    }
    float cv = 0.f;
    __syncthreads();
    if (tid < 64) L.ab.hm2[tid] = packh2(L.ab.hml[2*tid], L.ab.hml[2*tid+1]);
    __syncthreads();
    {
      const uint4* h4 = (const uint4*)L.ab.hm2;
      float g0 = a.Xd[(size_t)0*BB*G4 + b*G4 + tid], g1 = 0.f, g2 = 0.f, g3 = 0.f;
      #pragma unroll
      for (int q=0;q<16;q++){
        uint4 hv = h4[q];
        g0 = fdot2_(wdh[4*q+0], hv.x, g0);
        g1 = fdot2_(wdh[4*q+1], hv.y, g1);
        g2 = fdot2_(wdh[4*q+2], hv.z, g2);
        g3 = fdot2_(wdh[4*q+3], hv.w, g3);
      }
      L.ab.gates[tid] = (g0+g1)+(g2+g3);
    }
    __syncthreads();

    for (int it=0; it<NIT; ++it){
      if (it < NAB){
        #pragma unroll 1
        for (int j=0;j<KB;j++){
          int t = KB*it + j;
          if (j) __syncthreads();          // gates store of prev sub-step -> read
          if (t >= TT) break;
          int tn = (t+1 < TT) ? t+1 : 0;
          float xdn = a.Xd[(size_t)tn*BB*G4 + b*G4 + tid];   // prefetch
          bool valid = (slenb > t+1);
          if (tid < 128){
            float gi = L.ab.gates[tid];
            float gf = L.ab.gates[128+tid];
            float gg = L.ab.gates[256+tid];
            float go = L.ab.gates[384+tid];
            float ii = sigf(gi), ff = sigf(gf), g2 = tanh_(gg), oo = sigf(go);
            float cn = ff*creg + ii*g2;
            float hv = oo*tanh_(cn);
            if (valid) creg = cn;
            hmreg = valid ? hv : hmreg;
            L.ab.hnl[tid] = hv;
            L.ab.hml[tid] = hmreg;
            a.hn[((size_t)(t&HN_M)*BB + b)*HH + tid] = hv;
          }
          __syncthreads();                 // S1: hnl/hml visible
          if (tid < 64){
            L.ab.hn2[tid] = packh2(L.ab.hnl[2*tid], L.ab.hnl[2*tid+1]);
            L.ab.hm2[tid] = packh2(L.ab.hml[2*tid], L.ab.hml[2*tid+1]);
          }
          __syncthreads();                 // S2: hn2/hm2 visible
          if (tid < 128){
            const uint4* n4 = (const uint4*)L.ab.hn2;
            float u0 = b1r, u1 = 0.f, u2 = 0.f, u3 = 0.f;
            #pragma unroll
            for (int q=0;q<16;q++){
              uint4 nv = n4[q];
              u0 = fdot2_(L.ab.W1h2[(4*q+0)*128+tid], nv.x, u0);
              u1 = fdot2_(L.ab.W1h2[(4*q+1)*128+tid], nv.y, u1);
              u2 = fdot2_(L.ab.W1h2[(4*q+2)*128+tid], nv.z, u2);
              u3 = fdot2_(L.ab.W1h2[(4*q+3)*128+tid], nv.w, u3);
            }
            ((float*)L.ab.uhwc)[(tid>>1)*4 + (tid&1)] = (u0+u1)+(u2+u3);
          }
          __syncthreads();                 // S3: uh visible
          // ---- fused score + gates(t+1): independent op streams, ILP ----
          // gates write is race-free: all gates readers passed S1 (< S3);
          // next-step readers are ordered by the loop-top sync.
          float sc0 = 0.f, sc1 = 0.f;
          float g0 = xdn, g1 = 0.f, g2 = 0.f, g3 = 0.f;
          const uint4* h4 = (const uint4*)L.ab.hm2;
          #pragma unroll
          for (int k2=0;k2<64;k2++){
            if ((k2&3)==0){
              uint4 hv = h4[k2>>2];
              g0 = fdot2_(wdh[k2+0], hv.x, g0);
              g1 = fdot2_(wdh[k2+1], hv.y, g1);
              g2 = fdot2_(wdh[k2+2], hv.z, g2);
              g3 = fdot2_(wdh[k2+3], hv.w, g3);
            }
            unsigned tp = ts2[k2];
            float4 uw  = L.ab.uhwc[k2];    // one ds_read_b128 (broadcast)
            float2 w2v = L.ab.w2p[k2];     // one ds_read_b64  (broadcast)
            float p0 = hlo(tp) + uw.x + cv*uw.z;
            float p1 = hhi(tp) + uw.y + cv*uw.w;
            sc0 += tanh_(p0)*w2v.x;
            sc1 += tanh_(p1)*w2v.y;
          }
          L.ab.gates[tid] = (g0+g1)+(g2+g3);   // consumed at next loop-top
          // fused softmax: |sc| <= sum|w2| ~ 5, exp cannot overflow -> skip max
          float e = fexp(sc0 + sc1);
          int wid = tid>>6;
          float es = e;
          #pragma unroll
          for (int off=32;off>=1;off>>=1) es += __shfl_xor(es, off, 64);
          if ((tid&63)==0) L.ab.wredB[wid] = es;
          __syncthreads();                 // S4
          float ssum = 0.f;
          #pragma unroll
          for (int w8=0;w8<8;w8++) ssum += L.ab.wredB[w8];
          float at = e * rcpf_(ssum);
          a.attn[((size_t)(t&AT_M)*BB + b)*SS + tid] = at;
          float cl = fminf(cv, at);
          #pragma unroll
          for (int off=32;off>=1;off>>=1) cl += __shfl_xor(cl, off, 64);
          if ((tid&63)==0) L.ab.wredC[wid] = cl;
          __syncthreads();                 // S5
          if (tid==0){
            float cvs = 0.f;
            #pragma unroll
            for (int w8=0;w8<8;w8++) cvs += L.ab.wredC[w8];
            a.covloss[(t&CV_M)*BB + b] = cvs;
          }
          if (valid) cv += at;
        }
      }
      gbar(a.bar);
    }
  } else if (bid < 16){
    // ================= CTX: context = attn @ ts (lag 1 iteration) ===========
    int b = bid-8;
    int d = tid & 255, half = tid >> 8;
    unsigned tsr[128];
    #pragma unroll
    for (int s2=0;s2<128;s2++)
      tsr[s2] = a.ts_h[((((size_t)b*2 + half)*128) + s2)*256 + d];
    for (int it=0; it<NIT; ++it){
      if (it >= 1 && it <= NAB){
        #pragma unroll 1
        for (int j=0;j<KB;j++){
          int s = KB*(it-1) + j;
          if (s >= TT) break;
          L.cx.at[tid] = a.attn[((size_t)(s&AT_M)*BB + b)*SS + tid];
          __syncthreads();
          float acc = 0.f;
          const float* ap = L.cx.at + half*256;
          #pragma unroll
          for (int s2=0;s2<128;s2++){
            float2 av = *(const float2*)&ap[2*s2];
            unsigned tp = tsr[s2];
            acc += hlo(tp)*av.x + hhi(tp)*av.y;
          }
          L.cx.part[tid] = acc;
          __syncthreads();
          if (tid < 256)
            a.ctx[((size_t)(s&CX_M)*BB + b)*256 + tid] = L.cx.part[tid] + L.cx.part[256+tid];
        }
      }
      gbar(a.bar);
    }
  } else if (bid == 16){
    // ========= CB: target logit (lag 2 iters) + LSE/loss (lag 3 iters) ======
    int b = tid >> 6, l = tid & 63;
    int slenb = a.slen[b];
    if (tid == 0) L.cb.loss = 0.f;
    __syncthreads();
    for (int it=0; it<NIT; ++it){
      #pragma unroll 1
      for (int j=0;j<KB;j++){
        int ts = KB*(it-2) + j;
        if (ts >= 0 && ts < TT){
          int tp = a.summary[b*T1 + ts+1];
          float acc = 0.f;
          #pragma unroll
          for (int i=0;i<6;i++){
            int k = l + 64*i;
            float x = (k < 256) ? a.ctx[((size_t)(ts&CX_M)*BB + b)*256 + k]
                                : a.hn[((size_t)(ts&HN_M)*BB + b)*HH + (k-256)];
            float w = a.Wl[(size_t)tp*384 + k];
            acc += bf2f(f2bf(x)) * bfrnd(w);
          }
          #pragma unroll
          for (int off=32;off>=1;off>>=1) acc += __shfl_xor(acc, off, 64);
          if (l==0) L.cb.tgt[(ts&63)*BB + b] = acc + a.bl[tp];
        }
        int cs = KB*(it-3) + j;
        if (cs >= 0 && cs < TT){
          int slot = cs&PM_M;
          const float* pmp = a.pm + (size_t)slot*BB*CGB + b*CGB;
          const float* psp = a.ps + (size_t)slot*BB*CGB + b*CGB;
          float m = -1e30f;
          for (int jb=l; jb<CGB; jb+=64) m = fmaxf(m, pmp[jb]);
          #pragma unroll
          for (int off=32;off>=1;off>>=1) m = fmaxf(m, __shfl_xor(m, off, 64));
          float s = 0.f;
          for (int jb=l; jb<CGB; jb+=64) s += psp[jb]*fexp(pmp[jb]-m);
          #pragma unroll
          for (int off=32;off>=1;off>>=1) s += __shfl_xor(s, off, 64);
          __syncthreads();
          if (l==0){
            float lse = m + log2f_(s)*0.6931472f;
            bool val = slenb > cs+1;
            L.cb.red[b] = val ? (lse - L.cb.tgt[(cs&63)*BB+b] + GAMMA*a.covloss[(cs&CV_M)*BB+b]) : 0.f;
          }
          __syncthreads();
          if (tid==0){
            float sum = 0.f;
            #pragma unroll
            for (int b2=0;b2<BB;b2++) sum += L.cb.red[b2];
            L.cb.loss += sum;
          }
        }
      }
      if (it==NIT-1 && tid==0) a.out[0] = L.cb.loss*(1.0f/TT);
      gbar(a.bar);
    }
  } else {
    // ====== CG: vocab MFMA GEMM, Wl in registers (lag 2 iterations) =========
    int cb = bid-17;
    int lane = tid & 63, wid = tid >> 6;
    int quad = lane >> 4, col = lane & 15;
    uint4 wreg[24];
    float biasv[2];
    bool nOK[2];
    #pragma unroll
    for (int lt=0; lt<2; lt++){
      int lti = lt*8 + wid;
      bool gv = (lti < TPB);
      int g = cb*TPB + (gv ? lti : 0);
      int n = g*16 + col;
      int nc = (n < VV) ? n : (VV-1);
      const float* wr0 = a.Wl + (size_t)nc*384 + quad*8;
      #pragma unroll
      for (int ks=0; ks<12; ks++){
        float4 w0 = *((const float4*)(wr0 + ks*32));
        float4 w1 = *((const float4*)(wr0 + ks*32 + 4));
        wreg[lt*12+ks] = make_uint4(pack2rq(w0.x,w0.y), pack2rq(w0.z,w0.w),
                                    pack2rq(w1.x,w1.y), pack2rq(w1.z,w1.w));
      }
      nOK[lt] = gv && (n < VV);
      biasv[lt] = nOK[lt] ? a.bl[n] : 0.f;
    }
    for (int it=0; it<NIT; ++it){
      if (it >= 2 && it <= NAB+1){
        #pragma unroll 1
        for (int j=0;j<KB;j++){
          int s = KB*(it-2) + j;
          if (s >= TT) break;
          for (int f=tid; f<16*384; f+=512){
            int m2 = f/384, k = f - m2*384;
            float v = 0.f;
            if (m2 < 8) v = (k < 256) ? a.ctx[((size_t)(s&CX_M)*BB + m2)*256 + k]
                                      : a.hn[((size_t)(s&HN_M)*BB + m2)*HH + (k-256)];
            L.cg.xs[m2*392 + k] = f2bf(v);
          }
          __syncthreads();
          const unsigned short* ap = L.cg.xs + col*392 + quad*8;
          float mr[4], sr[4];
          #pragma unroll
          for (int r=0;r<4;r++){ mr[r] = -1e30f; sr[r] = 0.f; }
          #pragma unroll
          for (int lt=0; lt<2; lt++){
            cfrag acc; acc.x=0.f; acc.y=0.f; acc.z=0.f; acc.w=0.f;
            #pragma unroll
            for (int ks=0; ks<12; ks++){
              bfrag af = *((const bfrag*)(ap + ks*32));
              bfrag bf = __builtin_bit_cast(bfrag, wreg[lt*12+ks]);
              acc = __builtin_amdgcn_mfma_f32_16x16x32_bf16(af, bf, acc, 0,0,0);
            }
            #pragma unroll
            for (int r=0;r<4;r++){
              int mrow = quad*4 + r;
              float v = (mrow < 8 && nOK[lt]) ? (acc[r]+biasv[lt]) : -1e30f;
              float nm = fmaxf(mr[r], v);
              float ev = (v <= -1e29f) ? 0.f : fexp(v-nm);
              sr[r] = sr[r]*fexp(mr[r]-nm) + ev;
              mr[r] = nm;
            }
          }
          #pragma unroll
          for (int off=1; off<16; off<<=1){
            #pragma unroll
            for (int r=0;r<4;r++){
              float m2 = __shfl_xor(mr[r], off, 64);
              float s2 = __shfl_xor(sr[r], off, 64);
              float nm = fmaxf(mr[r], m2);
              sr[r] = sr[r]*fexp(mr[r]-nm) + s2*fexp(m2-nm);
              mr[r] = nm;
            }
          }
          if (col==0 && quad<2){
            #pragma unroll
            for (int r=0;r<4;r++){
              L.cg.rm[wid*8 + quad*4 + r] = mr[r];
              L.cg.rs[wid*8 + quad*4 + r] = sr[r];
            }
          }
          __syncthreads();
          if (tid < 8){
            float M = -1e30f, S = 0.f;
            #pragma unroll
            for (int w8=0; w8<8; w8++){
              float m2 = L.cg.rm[w8*8+tid], s2 = L.cg.rs[w8*8+tid];
              float nm = fmaxf(M, m2);
              S = S*fexp(M-nm) + s2*fexp(m2-nm);
              M = nm;
            }
            a.pm[(size_t)(s&PM_M)*BB*CGB + tid*CGB + cb] = M;
            a.ps[(size_t)(s&PM_M)*BB*CGB + tid*CGB + cb] = S;
          }
        }
      }
      gbar(a.bar);
    }
  }
}

// ---------------- host ----------------
extern "C" void kernel_launch(void* const* d_in, const int* in_sizes, int n_in,
                              void* d_out, int out_size, void* d_ws, size_t ws_size,
                              hipStream_t stream){
  const int* text      = (const int*)d_in[0];
  const int* tlen      = (const int*)d_in[1];
  const int* summary   = (const int*)d_in[2];
  const int* slen      = (const int*)d_in[3];
  const float* wv      = (const float*)d_in[4];
  const float* Wih_f   = (const float*)d_in[5];
  const float* Whh_f   = (const float*)d_in[6];
  const float* bih_f   = (const float*)d_in[7];
  const float* bhh_f   = (const float*)d_in[8];
  const float* Wih_b   = (const float*)d_in[9];
  const float* Whh_b   = (const float*)d_in[10];
  const float* bih_b   = (const float*)d_in[11];
  const float* bhh_b   = (const float*)d_in[12];
  const float* Wdih    = (const float*)d_in[13];
  const float* Wdhh    = (const float*)d_in[14];
  const float* bdih    = (const float*)d_in[15];
  const float* bdhh    = (const float*)d_in[16];
  const float* W1      = (const float*)d_in[17];
  const float* b1      = (const float*)d_in[18];
  const float* W2      = (const float*)d_in[19];
  const float* Wl      = (const float*)d_in[21];
  const float* bl      = (const float*)d_in[22];

  char* ws = (char*)d_ws;
  size_t off = 0;
  auto alloc = [&](size_t n)->void*{
    off = (off + 255) & ~(size_t)255;
    void* p = ws + off; off += n; return p;
  };

  // ---- decode-persistent region ----
  unsigned* W1h2   = (unsigned*)alloc((size_t)8192*4);
  unsigned* Wdh2T  = (unsigned*)alloc((size_t)64*512*4);
  float*    Xd     = (float*)alloc((size_t)TT*BB*G4*4);
  unsigned* ts_h   = (unsigned*)alloc((size_t)BB*2*128*256*4);
  unsigned* TS1Th  = (unsigned*)alloc((size_t)BB*64*512*4);
  float* W1c       = (float*)alloc((size_t)128*4);
  float* h0        = (float*)alloc(BB*HH*4);
  float* c0        = (float*)alloc(BB*HH*4);
  float* hn        = (float*)alloc((size_t)(HN_M+1)*BB*HH*4);
  float* ctx       = (float*)alloc((size_t)(CX_M+1)*BB*256*4);
  float* attn      = (float*)alloc((size_t)(AT_M+1)*BB*SS*4);
  float* covloss   = (float*)alloc((size_t)(CV_M+1)*BB*4);
  float* pm        = (float*)alloc((size_t)(PM_M+1)*BB*CGB*4);
  float* ps        = (float*)alloc((size_t)(PM_M+1)*BB*CGB*4);
  unsigned* bar    = (unsigned*)alloc(4096);

  // ---- encoder-transient region ----
  float* emb     = (float*)alloc((size_t)BB*SS*DD*4);
  float* Xf      = (float*)alloc(((size_t)BB*SS*G4 + 8*G4)*4);
  float* Xb      = (float*)alloc(((size_t)BB*SS*G4 + 8*G4)*4);
  float* WihT_f  = (float*)alloc((size_t)256*512*4);
  float* WihT_b  = (float*)alloc((size_t)256*512*4);
  unsigned* W2T_f= (unsigned*)alloc((size_t)64*512*4);
  unsigned* W2T_b= (unsigned*)alloc((size_t)64*512*4);
  float* out_f   = (float*)alloc((size_t)BB*SS*HH*4);
  float* out_r   = (float*)alloc((size_t)BB*SS*HH*4);
  float* W1aT    = (float*)alloc((size_t)256*128*4);
  int*   ridx    = (int*)  alloc((size_t)BB*SS*4);

  k_prep_small<<<1569,256,0,stream>>>(Wih_f,Wih_b,Whh_f,Whh_b,W1,Wdhh,
                                      WihT_f,WihT_b,W2T_f,W2T_b,W1aT,W1c,W1h2,Wdh2T);
  k_xd<<<TT,512,0,stream>>>(summary, wv, Wdih, bdih, bdhh, Xd, bar);
  k_embed<<<BB*SS,64,0,stream>>>(text, tlen, wv, emb, ridx);
  k_xgemm<<<512,256,0,stream>>>(emb, ridx, WihT_f, bih_f, bhh_f, Xf, 0);
  k_xgemm<<<512,256,0,stream>>>(emb, ridx, WihT_b, bih_b, bhh_b, Xb, 1);
  k_encoder<<<dim3(8,2),512,0,stream>>>(Xf,Xb,W2T_f,W2T_b,tlen,out_f,out_r,h0,c0);
  k_post<<<dim3(8,16),256,0,stream>>>(out_f,out_r,ridx,W1aT,ts_h,TS1Th);

  PArgs a;
  a.summary=summary; a.slen=slen;
  a.Xd=Xd; a.TS1Th=TS1Th; a.ts_h=ts_h;
  a.W1h2g=W1h2; a.W1c=W1c; a.W2=W2; a.b1=b1;
  a.Wdh2T=Wdh2T; a.Wl=Wl; a.bl=bl;
  a.h0=h0; a.c0=c0;
  a.hn=hn; a.ctx=ctx; a.attn=attn; a.covloss=covloss;
  a.pm=pm; a.ps=ps; a.bar=bar; a.out=(float*)d_out;

  k_decode<<<NBLK,512,0,stream>>>(a);
}

// Round 6
// 1349.204 us; speedup vs baseline: 1.2579x; 1.1937x over previous
//
#include <hip/hip_runtime.h>
#include <hip/hip_bf16.h>

#define VV 50000
#define DD 256
#define HH 128
#define G4 512
#define BB 8
#define SS 512
#define TT 100
#define T1 101
#define GAMMA 1.0f
#define LOG2E 1.44269504f
#define CGB 224              // GEMM blocks
#define TPB 14               // vocab 16-tiles per GEMM block (224*14*16 = 50176)
#define NBLK (25+CGB)        // 0-15 AB halves, 16-23 CTX, 24 combine, 25..248 GEMM

// ---- batched-barrier pipeline: KB decoder steps per device barrier ----
// KB* = sqrt(TT*B/(3p)) ~ 9 -> KB=10 (R5 post-mortem)
#define KB 10                // steps per barrier (TT % KB == 0)
#define NAB (TT/KB)          // AB-active iterations = 10
#define NIT (NAB+3)          // total iterations incl. 3 pipeline-drain lags = 13
// ring-buffer slot masks (depth >= KB*(lag+1), verified R1/R3):
#define AT_M 31              // attn  depth 32 (AB -> CTX, lag 1)
#define CX_M 31              // ctx   depth 32 (CTX -> CG/CB-tgt, lag 1)
#define HN_M 31              // hn    depth 32 (AB -> CG/CB, lag 2)
#define CV_M 63              // covloss depth 64 (AB -> CB-loss, lag 3)
#define PM_M 31              // pm/ps depth 32 (CG -> CB-loss, lag 1)

__device__ inline float rcpf_(float x){
#if __has_builtin(__builtin_amdgcn_rcpf)
  return __builtin_amdgcn_rcpf(x);
#else
  return 1.0f/x;
#endif
}
__device__ inline float exp2f_(float x){
#if __has_builtin(__builtin_amdgcn_exp2f)
  return __builtin_amdgcn_exp2f(x);
#else
  return exp2f(x);
#endif
}
__device__ inline float log2f_(float x){
#if __has_builtin(__builtin_amdgcn_logf)
  return __builtin_amdgcn_logf(x);
#else
  return log2f(x);
#endif
}
__device__ inline float fexp(float x){ return exp2f_(x*LOG2E); }
__device__ inline float sigf(float x){ return rcpf_(1.f + exp2f_(-x*LOG2E)); }
// tanh = 1 - 2/(e^2x+1): no clamp needed (inf -> 1, 0 -> -1), 5 ops, 2 trans
__device__ inline float tanh_(float x){
  float e = exp2f_(x*(2.0f*LOG2E));
  return 1.0f - 2.0f*rcpf_(e+1.0f);
}
__device__ inline unsigned short f2bf(float x){
  unsigned u = __float_as_uint(x);
  return (unsigned short)((u + 0x7fffu + ((u>>16)&1u)) >> 16);
}
__device__ inline float bf2f(unsigned short s){ return __uint_as_float(((unsigned)s)<<16); }
__device__ inline float bfrnd(float x){
  return __uint_as_float((__float_as_uint(x)+0x8000u)&0xffff0000u);
}
__device__ inline unsigned pack2rq(float a, float b){
#if __has_builtin(__builtin_amdgcn_perm)
  unsigned ua = __float_as_uint(a) + 0x8000u;
  unsigned ub = __float_as_uint(b) + 0x8000u;
  return __builtin_amdgcn_perm(ub, ua, 0x07060302u);
#else
  unsigned ra = (__float_as_uint(a)+0x8000u)>>16;
  unsigned rb = (__float_as_uint(b)+0x8000u)>>16;
  return ra | (rb<<16);
#endif
}

typedef __attribute__((ext_vector_type(2))) _Float16 h2v;
typedef __attribute__((ext_vector_type(8))) short bfrag;
typedef __attribute__((ext_vector_type(4))) float cfrag;

__device__ inline unsigned packh2(float a, float b){
  unsigned short ha = __builtin_bit_cast(unsigned short, (_Float16)a);
  unsigned short hb = __builtin_bit_cast(unsigned short, (_Float16)b);
  return (unsigned)ha | ((unsigned)hb<<16);
}
__device__ inline float fdot2_(unsigned a, unsigned b, float c){
#if __has_builtin(__builtin_amdgcn_fdot2)
  return __builtin_amdgcn_fdot2(__builtin_bit_cast(h2v, a), __builtin_bit_cast(h2v, b), c, false);
#else
  h2v av = __builtin_bit_cast(h2v, a), bv = __builtin_bit_cast(h2v, b);
  return c + (float)av.x*(float)bv.x + (float)av.y*(float)bv.y;
#endif
}
__device__ inline float hlo(unsigned u){ return (float)__builtin_bit_cast(h2v, u).x; }
__device__ inline float hhi(unsigned u){ return (float)__builtin_bit_cast(h2v, u).y; }

// ---- single-scalar pair exchange: payload+tag in one 64-bit agent atomic ----
__device__ inline void pub64(unsigned long long* p, unsigned long long v){
  __hip_atomic_store(p, v, __ATOMIC_RELEASE, __HIP_MEMORY_SCOPE_AGENT);
}
__device__ inline unsigned poll64(unsigned long long* p, unsigned hi){
  unsigned long long v;
  do { v = __hip_atomic_load(p, __ATOMIC_ACQUIRE, __HIP_MEMORY_SCOPE_AGENT); }
  while ((unsigned)(v>>32) != hi);
  return (unsigned)v;
}

// ------ hierarchical device-scope barrier: 8 padded group lines + root ------
// bar layout (dwords): lcnt[g] @ 64*g (g=0..7), gcnt @ 512, gen @ 576,
//                      es-exchange u64 slots @ 640.. (16 slots)
__device__ inline void gbar(unsigned* bar){
  __syncthreads();
  if (threadIdx.x == 0){
    __threadfence();
    int g = blockIdx.x & 7;
    unsigned gsz = (unsigned)((NBLK + 7 - g) >> 3);
    unsigned gen = __hip_atomic_load(bar+576, __ATOMIC_RELAXED, __HIP_MEMORY_SCOPE_AGENT);
    unsigned old = __hip_atomic_fetch_add(bar+64*g, 1u, __ATOMIC_ACQ_REL, __HIP_MEMORY_SCOPE_AGENT);
    if (old == gsz-1u){
      __hip_atomic_store(bar+64*g, 0u, __ATOMIC_RELAXED, __HIP_MEMORY_SCOPE_AGENT);
      unsigned go = __hip_atomic_fetch_add(bar+512, 1u, __ATOMIC_ACQ_REL, __HIP_MEMORY_SCOPE_AGENT);
      if (go == 7u){
        __hip_atomic_store(bar+512, 0u, __ATOMIC_RELAXED, __HIP_MEMORY_SCOPE_AGENT);
        __hip_atomic_fetch_add(bar+576, 1u, __ATOMIC_RELEASE, __HIP_MEMORY_SCOPE_AGENT);
      } else {
        while (__hip_atomic_load(bar+576, __ATOMIC_RELAXED, __HIP_MEMORY_SCOPE_AGENT) == gen)
          __builtin_amdgcn_s_sleep(2);
      }
    } else {
      while (__hip_atomic_load(bar+576, __ATOMIC_RELAXED, __HIP_MEMORY_SCOPE_AGENT) == gen)
        __builtin_amdgcn_s_sleep(2);
    }
    __threadfence();
  }
  __syncthreads();
}

// ---------------- prep: small weight transposes/packs ----------------
__global__ void __launch_bounds__(256) k_prep_small(
    const float* Wih_f, const float* Wih_b, const float* Whh_f, const float* Whh_b,
    const float* W1, const float* Wdhh,
    float* WihT_f, float* WihT_b, unsigned* W2T_f, unsigned* W2T_b,
    float* W1aT, float* W1c, unsigned* W1h2, unsigned* Wdh2T){
  int i = blockIdx.x*256 + threadIdx.x;
  if (i < 131072){ int k = i>>9, j = i&511; WihT_f[i] = Wih_f[j*DD + k]; return; }
  i -= 131072;
  if (i < 131072){ int k = i>>9, j = i&511; WihT_b[i] = Wih_b[j*DD + k]; return; }
  i -= 131072;
  if (i < 32768){ int k2 = i>>9, j = i&511;
    W2T_f[i] = packh2(Whh_f[j*HH + 2*k2], Whh_f[j*HH + 2*k2+1]); return; }
  i -= 32768;
  if (i < 32768){ int k2 = i>>9, j = i&511;
    W2T_b[i] = packh2(Whh_b[j*HH + 2*k2], Whh_b[j*HH + 2*k2+1]); return; }
  i -= 32768;
  if (i < 32768){ int d = i>>7, k = i&127; W1aT[i] = W1[k*385 + d]; return; }
  i -= 32768;
  if (i < 128){ W1c[i] = W1[i*385 + 384]; return; }
  i -= 128;
  if (i < 8192){ int j2 = i>>7, col = i&127;
    W1h2[i] = packh2(W1[col*385 + 256 + 2*j2], W1[col*385 + 256 + 2*j2+1]); return; }
  i -= 8192;
  if (i < 32768){ int q = i>>9, jj = i&511;
    Wdh2T[i] = packh2(Wdhh[jj*HH + 2*q], Wdhh[jj*HH + 2*q+1]); return; }
}

// ---------------- Xd[t][b][j] = Wdih@x + bdih + bdhh ; also zero barrier -----
__global__ void __launch_bounds__(512) k_xd(const int* summary, const float* wv,
    const float* Wdih, const float* bdih, const float* bdhh,
    float* Xd, unsigned* bar){
  __shared__ float xsl[8][256];
  int t = blockIdx.x, tid = threadIdx.x;
  for (int f=tid; f<2048; f+=512){
    int b = f>>8, k = f&255;
    xsl[b][k] = wv[(size_t)summary[b*T1 + t]*DD + k];
  }
  if (blockIdx.x==0){ for (int f=tid; f<1024; f+=512) bar[f] = 0u; }
  __syncthreads();
  int jj = tid;
  float base = bdih[jj] + bdhh[jj];
  const float4* wr = (const float4*)(Wdih + (size_t)jj*DD);
  float acc[8];
  #pragma unroll
  for (int b=0;b<8;b++) acc[b]=0.f;
  for (int q=0;q<64;q++){
    float4 w = wr[q];
    #pragma unroll
    for (int b=0;b<8;b++)
      acc[b] += w.x*xsl[b][4*q] + w.y*xsl[b][4*q+1] + w.z*xsl[b][4*q+2] + w.w*xsl[b][4*q+3];
  }
  #pragma unroll
  for (int b=0;b<8;b++) Xd[((size_t)t*BB + b)*G4 + jj] = base + acc[b];
}

// ---------------- embedding gather + ridx ----------------
__global__ void k_embed(const int* text, const int* tlen, const float* wv,
                        float* emb, int* ridx){
  int blk = blockIdx.x;
  int b = blk>>9, s = blk&511;
  int tok = text[blk];
  const float4* src = (const float4*)(wv + (size_t)tok*DD);
  float4* dst = (float4*)(emb + (size_t)blk*DD);
  dst[threadIdx.x] = src[threadIdx.x];
  if (threadIdx.x==0){ int len = tlen[b]; ridx[blk] = (s < len) ? (len-1-s) : s; }
}

// ---------------- X = emb @ Wih^T + bih + bhh ----------------
__global__ void __launch_bounds__(256) k_xgemm(const float* emb, const int* ridx,
    const float* WihT, const float* bi, const float* bh, float* X, int rev){
  __shared__ float e_l[8][256];
  int tid = threadIdx.x;
  int g0 = blockIdx.x*8;
  int b = g0>>9;
  for (int r=0;r<8;r++){
    int s = (g0+r)&511;
    int src = rev ? ridx[b*SS + s] : s;
    e_l[r][tid] = emb[((size_t)(b*SS+src))*DD + tid];
  }
  __syncthreads();
  int j0 = tid, j1 = tid+256;
  float acc0[8], acc1[8];
  #pragma unroll
  for (int r=0;r<8;r++){ acc0[r]=0.f; acc1[r]=0.f; }
  for (int k=0;k<256;k++){
    float w0 = WihT[k*G4 + j0];
    float w1 = WihT[k*G4 + j1];
    #pragma unroll
    for (int r=0;r<8;r++){ float e = e_l[r][k]; acc0[r] += e*w0; acc1[r] += e*w1; }
  }
  float bb0 = bi[j0]+bh[j0], bb1 = bi[j1]+bh[j1];
  for (int r=0;r<8;r++){
    X[((size_t)(g0+r))*G4 + j0] = acc0[r] + bb0;
    X[((size_t)(g0+r))*G4 + j1] = acc1[r] + bb1;
  }
}

// ------ encoder: register Whh (f16), X preload x8, out buffered x8 ----------
__global__ void __launch_bounds__(512) k_encoder(const float* Xf, const float* Xb,
    const unsigned* W2Tf, const unsigned* W2Tb, const int* tlen,
    float* out_f, float* out_r, float* h0, float* c0){
  __shared__ float g_l[512];
  __shared__ __align__(16) unsigned h2_l[64];
  int tid = threadIdx.x;
  int b = blockIdx.x, dir = blockIdx.y;
  const float* X = dir ? Xb : Xf;
  const unsigned* WT = dir ? W2Tb : W2Tf;
  float* out = dir ? out_r : out_f;
  unsigned w[64];
  #pragma unroll
  for (int k2=0;k2<64;k2++) w[k2] = WT[k2*G4 + tid];
  if (tid < 64) h2_l[tid] = 0u;
  float creg = 0.f, hreg = 0.f;
  int len = tlen[b];
  __syncthreads();
  for (int t0=0;t0<len;t0+=8){
    float x8[8];
    #pragma unroll
    for (int i=0;i<8;i++) x8[i] = X[(size_t)(b*SS+t0+i)*G4 + tid];
    float out8[8];
    #pragma unroll
    for (int i=0;i<8;i++){
      int t = t0+i;
      if (t >= len) break;
      float a0 = x8[i], a1 = 0.f, a2 = 0.f, a3 = 0.f;
      const uint4* h4 = (const uint4*)h2_l;
      #pragma unroll
      for (int q=0;q<16;q++){
        uint4 hv = h4[q];
        a0 = fdot2_(w[4*q+0], hv.x, a0);
        a1 = fdot2_(w[4*q+1], hv.y, a1);
        a2 = fdot2_(w[4*q+2], hv.z, a2);
        a3 = fdot2_(w[4*q+3], hv.w, a3);
      }
      g_l[tid] = (a0+a1)+(a2+a3);
      __syncthreads();
      if (tid < 128){
        float ii = sigf(g_l[tid]);
        float ff = sigf(g_l[128+tid]);
        float gg = tanh_(g_l[256+tid]);
        float oo = sigf(g_l[384+tid]);
        creg = ff*creg + ii*gg;
        float hn = oo*tanh_(creg);
        out8[i] = hn;
        hreg = hn;
        ((_Float16*)h2_l)[tid] = (_Float16)hn;
      }
      __syncthreads();
    }
    if (tid < 128){
      int nend = (len - t0 < 8) ? (len - t0) : 8;
      #pragma unroll 8
      for (int i=0;i<nend;i++) out[((size_t)(b*SS+t0+i))*HH + tid] = out8[i];
    }
  }
  if (dir==0 && tid<128){ h0[b*HH+tid]=hreg; c0[b*HH+tid]=creg; }
  for (int f = tid; f < (SS-len)*HH; f += 512){
    int s = len + (f>>7), j = f&127;
    out[((size_t)(b*SS+s))*HH + j] = 0.f;
  }
}

// ------- post-encoder: ts_h (f16 pairs over s) + TS1Th (f16 pairs over k) ----
__global__ void __launch_bounds__(256) k_post(const float* out_f, const float* out_r,
    const int* ridx, const float* W1aT, unsigned* ts_h, unsigned* TS1Th){
  __shared__ float ts_l[128*33 + 64];
  int tid = threadIdx.x;
  int b = blockIdx.x, chunk = blockIdx.y;
  int s0 = chunk*32;
  for (int it=0; it<32; ++it){
    int s = s0 + it;
    int d = tid;
    float v;
    if (d < 128) v = out_f[((size_t)(b*SS+s))*HH + d];
    else        v = out_r[((size_t)(b*SS + ridx[b*SS+s]))*HH + (d-128)];
    ts_l[it*256 + d] = v;
  }
  __syncthreads();
  for (int f=tid; f<16*256; f+=256){
    int it2 = f>>8, d = f&255;
    unsigned p = packh2(ts_l[(2*it2)*256 + d], ts_l[(2*it2+1)*256 + d]);
    ts_h[((((size_t)b*2 + (s0>>8))*128) + (((s0&255)>>1) + it2))*256 + d] = p;
  }
  int k = tid & 127, half = tid >> 7;
  float acc[16];
  #pragma unroll
  for (int i=0;i<16;i++) acc[i]=0.f;
  for (int d=0;d<256;d++){
    float w = W1aT[d*128 + k];
    #pragma unroll
    for (int i=0;i<16;i++) acc[i] += ts_l[(half*16+i)*256 + d]*w;
  }
  __syncthreads();
  #pragma unroll
  for (int i=0;i<16;i++) ts_l[k*33 + half*16 + i] = acc[i];
  __syncthreads();
  for (int f=tid; f<64*32; f+=256){
    int k2 = f>>5, sl = f&31;
    unsigned p = packh2(ts_l[(2*k2)*33 + sl], ts_l[(2*k2+1)*33 + sl]);
    TS1Th[((size_t)b*64 + k2)*512 + (s0 + sl)] = p;
  }
}

// ---------------- persistent decoder ----------------
struct PArgs {
  const int* summary; const int* slen;
  const float* Xd; const unsigned* TS1Th; const unsigned* ts_h;
  const unsigned* W1h2g; const float* W1c; const float* W2; const float* b1;
  const unsigned* Wdh2T; const float* Wl; const float* bl;
  const float* h0; const float* c0;
  float* hn; float* ctx; float* attn; float* covloss;
  float* pm; float* ps; unsigned* bar; float* out;
};

struct __align__(16) LdsAB {
  unsigned W1h2[8192];          // 32768 B
  float gates[512];
  float hnl[128], hml[128];
  unsigned hn2[64], hm2[64];    // 16B-aligned
  float4 uhwc[64];              // {uh0, uh1, wc0, wc1}
  float2 w2p[64];               // {w20, w21}
  float wredB[8], wredC[8];
  float ssumv;
};
struct LdsCG { unsigned short xs[16*392]; float rm[64], rs[64]; };
struct LdsCTX { float at[512]; float part[512]; };
struct LdsCB { float tgt[32*BB]; float red[8]; float loss; };
union LdsU { LdsAB ab; LdsCG cg; LdsCTX cx; LdsCB cb; };

__global__ void __launch_bounds__(512,1) k_decode(PArgs a){
  __shared__ LdsU L;
  int bid = blockIdx.x, tid = threadIdx.x;

  if (bid < 16){
    // ========== AB half-block: positions [half*256, half*256+256) ==========
    // LSTM cell / gates / uh replicated bit-identically on both halves (no
    // recurrence exchange). Per-step cross-CU dependency: softmax denominator
    // only -- one scalar via 64-bit tagged agent atomic.
    int b = bid >> 1, half = bid & 1;
    int slenb = a.slen[b];
    int kh = tid & 1;                 // k-half within position pair
    int sg = half*256 + (tid >> 1);   // global position owned by the pair
    unsigned long long* slots = (unsigned long long*)(a.bar + 640);
    float b1r = (tid < 128) ? a.b1[tid] : 0.f;
    if (tid < 64){
      L.ab.uhwc[tid] = make_float4(0.f, 0.f, a.W1c[2*tid], a.W1c[2*tid+1]);
      L.ab.w2p[tid]  = make_float2(a.W2[2*tid], a.W2[2*tid+1]);
    }
    for (int f=tid; f<8192; f+=512) L.ab.W1h2[f] = a.W1h2g[f];
    unsigned ts2[32];                 // this thread's 32 k2 rows at position sg
    #pragma unroll
    for (int i=0;i<32;i++) ts2[i] = a.TS1Th[((size_t)b*64 + kh*32 + i)*512 + sg];
    unsigned wdh[64];                 // gates: full j=tid column
    #pragma unroll
    for (int q=0;q<64;q++) wdh[q] = a.Wdh2T[q*512 + tid];
    float creg = 0.f, hmreg = 0.f;
    if (tid < 128){
      creg  = a.c0[b*HH+tid];
      hmreg = a.h0[b*HH+tid];
      L.ab.hml[tid] = hmreg;
    }
    float cv = 0.f;                   // coverage of position sg (both lanes of pair)
    __syncthreads();
    if (tid < 64) L.ab.hm2[tid] = packh2(L.ab.hml[2*tid], L.ab.hml[2*tid+1]);
    __syncthreads();
    {
      const uint4* h4 = (const uint4*)L.ab.hm2;
      float g0 = a.Xd[(size_t)0*BB*G4 + b*G4 + tid], g1 = 0.f, g2 = 0.f, g3 = 0.f;
      #pragma unroll
      for (int q=0;q<16;q++){
        uint4 hv = h4[q];
        g0 = fdot2_(wdh[4*q+0], hv.x, g0);
        g1 = fdot2_(wdh[4*q+1], hv.y, g1);
        g2 = fdot2_(wdh[4*q+2], hv.z, g2);
        g3 = fdot2_(wdh[4*q+3], hv.w, g3);
      }
      L.ab.gates[tid] = (g0+g1)+(g2+g3);
    }
    __syncthreads();

    for (int it=0; it<NIT; ++it){
      if (it < NAB){
        #pragma unroll 1
        for (int j=0;j<KB;j++){
          int t = KB*it + j;
          if (j) __syncthreads();          // gates store of prev sub-step -> read
          if (t >= TT) break;
          int tn = (t+1 < TT) ? t+1 : 0;
          float xdn = a.Xd[(size_t)tn*BB*G4 + b*G4 + tid];   // prefetch
          bool valid = (slenb > t+1);
          if (tid < 128){
            float gi = L.ab.gates[tid];
            float gf = L.ab.gates[128+tid];
            float gg = L.ab.gates[256+tid];
            float go = L.ab.gates[384+tid];
            float ii = sigf(gi), ff = sigf(gf), g2 = tanh_(gg), oo = sigf(go);
            float cn = ff*creg + ii*g2;
            float hv = oo*tanh_(cn);
            if (valid) creg = cn;
            hmreg = valid ? hv : hmreg;
            L.ab.hnl[tid] = hv;
            L.ab.hml[tid] = hmreg;
            if (half==0) a.hn[((size_t)(t&HN_M)*BB + b)*HH + tid] = hv;
          }
          __syncthreads();                 // S1: hnl/hml visible
          if (tid < 64){
            L.ab.hn2[tid] = packh2(L.ab.hnl[2*tid], L.ab.hnl[2*tid+1]);
            L.ab.hm2[tid] = packh2(L.ab.hml[2*tid], L.ab.hml[2*tid+1]);
          }
          __syncthreads();                 // S2: hn2/hm2 visible
          if (tid < 128){
            const uint4* n4 = (const uint4*)L.ab.hn2;
            float u0 = b1r, u1 = 0.f, u2 = 0.f, u3 = 0.f;
            #pragma unroll
            for (int q=0;q<16;q++){
              uint4 nv = n4[q];
              u0 = fdot2_(L.ab.W1h2[(4*q+0)*128+tid], nv.x, u0);
              u1 = fdot2_(L.ab.W1h2[(4*q+1)*128+tid], nv.y, u1);
              u2 = fdot2_(L.ab.W1h2[(4*q+2)*128+tid], nv.z, u2);
              u3 = fdot2_(L.ab.W1h2[(4*q+3)*128+tid], nv.w, u3);
            }
            ((float*)L.ab.uhwc)[(tid>>1)*4 + (tid&1)] = (u0+u1)+(u2+u3);
          }
          __syncthreads();                 // S3: uh visible
          // ---- fused half-score (32 k2) + full gates(t+1) ----
          float sc0 = 0.f, sc1 = 0.f;
          float g0 = xdn, g1 = 0.f, g2 = 0.f, g3 = 0.f;
          const uint4* h4 = (const uint4*)L.ab.hm2;
          uint4 hv;
          #pragma unroll
          for (int i=0;i<32;i++){
            if ((i&1)==0){
              hv = h4[i>>1];
              g0 = fdot2_(wdh[2*i],   hv.x, g0);
              g1 = fdot2_(wdh[2*i+1], hv.y, g1);
            } else {
              g2 = fdot2_(wdh[2*i],   hv.z, g2);
              g3 = fdot2_(wdh[2*i+1], hv.w, g3);
            }
            int k2 = kh*32 + i;
            unsigned tp = ts2[i];
            float4 uw  = L.ab.uhwc[k2];    // 2-address/wave broadcast (free)
            float2 w2v = L.ab.w2p[k2];
            float p0 = hlo(tp) + uw.x + cv*uw.z;
            float p1 = hhi(tp) + uw.y + cv*uw.w;
            sc0 += tanh_(p0)*w2v.x;
            sc1 += tanh_(p1)*w2v.y;
          }
          L.ab.gates[tid] = (g0+g1)+(g2+g3);   // consumed next loop-top
          float sc = sc0 + sc1;
          sc += __shfl_xor(sc, 1, 64);         // combine k-halves of the pair
          float e = fexp(sc);                  // |sc| bounded -> skip max
          float es = kh ? 0.f : e;             // count each position once
          #pragma unroll
          for (int off=32;off>=1;off>>=1) es += __shfl_xor(es, off, 64);
          int wid = tid>>6;
          if ((tid&63)==0) L.ab.wredB[wid] = es;
          __syncthreads();                 // S4
          if (tid==0){
            float esH = 0.f;
            #pragma unroll
            for (int w8=0;w8<8;w8++) esH += L.ab.wredB[w8];
            pub64(&slots[b*2+half],
                  ((unsigned long long)(t+1)<<32) | (unsigned long long)__float_as_uint(esH));
            unsigned ob = poll64(&slots[b*2+(half^1)], (unsigned)(t+1));
            L.ab.ssumv = esH + __uint_as_float(ob);
          }
          __syncthreads();                 // S5: ssum ready
          float at = e * rcpf_(L.ab.ssumv);
          if (kh==0) a.attn[((size_t)(t&AT_M)*BB + b)*SS + sg] = at;
          float cl = kh ? 0.f : fminf(cv, at);
          #pragma unroll
          for (int off=32;off>=1;off>>=1) cl += __shfl_xor(cl, off, 64);
          if ((tid&63)==0) L.ab.wredC[wid] = cl;
          __syncthreads();                 // S6
          if (tid==0){
            float cvs = 0.f;
            #pragma unroll
            for (int w8=0;w8<8;w8++) cvs += L.ab.wredC[w8];
            a.covloss[((t&CV_M)*BB + b)*2 + half] = cvs;   // per-half partial
          }
          if (valid) cv += at;
        }
      }
      gbar(a.bar);
    }
  } else if (bid < 24){
    // ================= CTX: context = attn @ ts (lag 1 iteration) ===========
    int b = bid-16;
    int d = tid & 255, half = tid >> 8;
    unsigned tsr[128];
    #pragma unroll
    for (int s2=0;s2<128;s2++)
      tsr[s2] = a.ts_h[((((size_t)b*2 + half)*128) + s2)*256 + d];
    for (int it=0; it<NIT; ++it){
      if (it >= 1 && it <= NAB){
        #pragma unroll 1
        for (int j=0;j<KB;j++){
          int s = KB*(it-1) + j;
          if (s >= TT) break;
          L.cx.at[tid] = a.attn[((size_t)(s&AT_M)*BB + b)*SS + tid];
          __syncthreads();
          float acc = 0.f;
          const float* ap = L.cx.at + half*256;
          #pragma unroll
          for (int s2=0;s2<128;s2++){
            float2 av = *(const float2*)&ap[2*s2];
            unsigned tp = tsr[s2];
            acc += hlo(tp)*av.x + hhi(tp)*av.y;
          }
          L.cx.part[tid] = acc;
          __syncthreads();
          if (tid < 256)
            a.ctx[((size_t)(s&CX_M)*BB + b)*256 + tid] = L.cx.part[tid] + L.cx.part[256+tid];
        }
      }
      gbar(a.bar);
    }
  } else if (bid == 24){
    // ========= CB: target logit (lag 2 iters) + LSE/loss (lag 3 iters) ======
    int b = tid >> 6, l = tid & 63;
    int slenb = a.slen[b];
    if (tid == 0) L.cb.loss = 0.f;
    __syncthreads();
    for (int it=0; it<NIT; ++it){
      #pragma unroll 1
      for (int j=0;j<KB;j++){
        int ts = KB*(it-2) + j;
        if (ts >= 0 && ts < TT){
          int tp = a.summary[b*T1 + ts+1];
          float acc = 0.f;
          #pragma unroll
          for (int i=0;i<6;i++){
            int k = l + 64*i;
            float x = (k < 256) ? a.ctx[((size_t)(ts&CX_M)*BB + b)*256 + k]
                                : a.hn[((size_t)(ts&HN_M)*BB + b)*HH + (k-256)];
            float w = a.Wl[(size_t)tp*384 + k];
            acc += bf2f(f2bf(x)) * bfrnd(w);
          }
          #pragma unroll
          for (int off=32;off>=1;off>>=1) acc += __shfl_xor(acc, off, 64);
          if (l==0) L.cb.tgt[(ts&31)*BB + b] = acc + a.bl[tp];
        }
        int cs = KB*(it-3) + j;
        if (cs >= 0 && cs < TT){
          int slot = cs&PM_M;
          const float* pmp = a.pm + (size_t)slot*BB*CGB + b*CGB;
          const float* psp = a.ps + (size_t)slot*BB*CGB + b*CGB;
          float m = -1e30f;
          for (int jb=l; jb<CGB; jb+=64) m = fmaxf(m, pmp[jb]);
          #pragma unroll
          for (int off=32;off>=1;off>>=1) m = fmaxf(m, __shfl_xor(m, off, 64));
          float s = 0.f;
          for (int jb=l; jb<CGB; jb+=64) s += psp[jb]*fexp(pmp[jb]-m);
          #pragma unroll
          for (int off=32;off>=1;off>>=1) s += __shfl_xor(s, off, 64);
          __syncthreads();
          if (l==0){
            float lse = m + log2f_(s)*0.6931472f;
            bool val = slenb > cs+1;
            float cvs = a.covloss[((cs&CV_M)*BB + b)*2 + 0]
                      + a.covloss[((cs&CV_M)*BB + b)*2 + 1];
            L.cb.red[b] = val ? (lse - L.cb.tgt[(cs&31)*BB+b] + GAMMA*cvs) : 0.f;
          }
          __syncthreads();
          if (tid==0){
            float sum = 0.f;
            #pragma unroll
            for (int b2=0;b2<BB;b2++) sum += L.cb.red[b2];
            L.cb.loss += sum;
          }
        }
      }
      if (it==NIT-1 && tid==0) a.out[0] = L.cb.loss*(1.0f/TT);
      gbar(a.bar);
    }
  } else {
    // ====== CG: vocab MFMA GEMM, Wl in registers (lag 2 iterations) =========
    int cb = bid-25;
    int lane = tid & 63, wid = tid >> 6;
    int quad = lane >> 4, col = lane & 15;
    uint4 wreg[24];
    float biasv[2];
    bool nOK[2];
    #pragma unroll
    for (int lt=0; lt<2; lt++){
      int lti = lt*8 + wid;
      bool gv = (lti < TPB);
      int g = cb*TPB + (gv ? lti : 0);
      int n = g*16 + col;
      int nc = (n < VV) ? n : (VV-1);
      const float* wr0 = a.Wl + (size_t)nc*384 + quad*8;
      #pragma unroll
      for (int ks=0; ks<12; ks++){
        float4 w0 = *((const float4*)(wr0 + ks*32));
        float4 w1 = *((const float4*)(wr0 + ks*32 + 4));
        wreg[lt*12+ks] = make_uint4(pack2rq(w0.x,w0.y), pack2rq(w0.z,w0.w),
                                    pack2rq(w1.x,w1.y), pack2rq(w1.z,w1.w));
      }
      nOK[lt] = gv && (n < VV);
      biasv[lt] = nOK[lt] ? a.bl[n] : 0.f;
    }
    for (int it=0; it<NIT; ++it){
      if (it >= 2 && it <= NAB+1){
        #pragma unroll 1
        for (int j=0;j<KB;j++){
          int s = KB*(it-2) + j;
          if (s >= TT) break;
          for (int f=tid; f<16*384; f+=512){
            int m2 = f/384, k = f - m2*384;
            float v = 0.f;
            if (m2 < 8) v = (k < 256) ? a.ctx[((size_t)(s&CX_M)*BB + m2)*256 + k]
                                      : a.hn[((size_t)(s&HN_M)*BB + m2)*HH + (k-256)];
            L.cg.xs[m2*392 + k] = f2bf(v);
          }
          __syncthreads();
          const unsigned short* ap = L.cg.xs + col*392 + quad*8;
          float mr[4], sr[4];
          #pragma unroll
          for (int r=0;r<4;r++){ mr[r] = -1e30f; sr[r] = 0.f; }
          #pragma unroll
          for (int lt=0; lt<2; lt++){
            cfrag acc; acc.x=0.f; acc.y=0.f; acc.z=0.f; acc.w=0.f;
            #pragma unroll
            for (int ks=0; ks<12; ks++){
              bfrag af = *((const bfrag*)(ap + ks*32));
              bfrag bf = __builtin_bit_cast(bfrag, wreg[lt*12+ks]);
              acc = __builtin_amdgcn_mfma_f32_16x16x32_bf16(af, bf, acc, 0,0,0);
            }
            #pragma unroll
            for (int r=0;r<4;r++){
              int mrow = quad*4 + r;
              float v = (mrow < 8 && nOK[lt]) ? (acc[r]+biasv[lt]) : -1e30f;
              float nm = fmaxf(mr[r], v);
              float ev = (v <= -1e29f) ? 0.f : fexp(v-nm);
              sr[r] = sr[r]*fexp(mr[r]-nm) + ev;
              mr[r] = nm;
            }
          }
          #pragma unroll
          for (int off=1; off<16; off<<=1){
            #pragma unroll
            for (int r=0;r<4;r++){
              float m2 = __shfl_xor(mr[r], off, 64);
              float s2 = __shfl_xor(sr[r], off, 64);
              float nm = fmaxf(mr[r], m2);
              sr[r] = sr[r]*fexp(mr[r]-nm) + s2*fexp(m2-nm);
              mr[r] = nm;
            }
          }
          if (col==0 && quad<2){
            #pragma unroll
            for (int r=0;r<4;r++){
              L.cg.rm[wid*8 + quad*4 + r] = mr[r];
              L.cg.rs[wid*8 + quad*4 + r] = sr[r];
            }
          }
          __syncthreads();
          if (tid < 8){
            float M = -1e30f, S = 0.f;
            #pragma unroll
            for (int w8=0; w8<8; w8++){
              float m2 = L.cg.rm[w8*8+tid], s2 = L.cg.rs[w8*8+tid];
              float nm = fmaxf(M, m2);
              S = S*fexp(M-nm) + s2*fexp(m2-nm);
              M = nm;
            }
            a.pm[(size_t)(s&PM_M)*BB*CGB + tid*CGB + cb] = M;
            a.ps[(size_t)(s&PM_M)*BB*CGB + tid*CGB + cb] = S;
          }
        }
      }
      gbar(a.bar);
    }
  }
}

// ---------------- host ----------------
extern "C" void kernel_launch(void* const* d_in, const int* in_sizes, int n_in,
                              void* d_out, int out_size, void* d_ws, size_t ws_size,
                              hipStream_t stream){
  const int* text      = (const int*)d_in[0];
  const int* tlen      = (const int*)d_in[1];
  const int* summary   = (const int*)d_in[2];
  const int* slen      = (const int*)d_in[3];
  const float* wv      = (const float*)d_in[4];
  const float* Wih_f   = (const float*)d_in[5];
  const float* Whh_f   = (const float*)d_in[6];
  const float* bih_f   = (const float*)d_in[7];
  const float* bhh_f   = (const float*)d_in[8];
  const float* Wih_b   = (const float*)d_in[9];
  const float* Whh_b   = (const float*)d_in[10];
  const float* bih_b   = (const float*)d_in[11];
  const float* bhh_b   = (const float*)d_in[12];
  const float* Wdih    = (const float*)d_in[13];
  const float* Wdhh    = (const float*)d_in[14];
  const float* bdih    = (const float*)d_in[15];
  const float* bdhh    = (const float*)d_in[16];
  const float* W1      = (const float*)d_in[17];
  const float* b1      = (const float*)d_in[18];
  const float* W2      = (const float*)d_in[19];
  const float* Wl      = (const float*)d_in[21];
  const float* bl      = (const float*)d_in[22];

  char* ws = (char*)d_ws;
  size_t off = 0;
  auto alloc = [&](size_t n)->void*{
    off = (off + 255) & ~(size_t)255;
    void* p = ws + off; off += n; return p;
  };

  // ---- decode-persistent region ----
  unsigned* W1h2   = (unsigned*)alloc((size_t)8192*4);
  unsigned* Wdh2T  = (unsigned*)alloc((size_t)64*512*4);
  float*    Xd     = (float*)alloc((size_t)TT*BB*G4*4);
  unsigned* ts_h   = (unsigned*)alloc((size_t)BB*2*128*256*4);
  unsigned* TS1Th  = (unsigned*)alloc((size_t)BB*64*512*4);
  float* W1c       = (float*)alloc((size_t)128*4);
  float* h0        = (float*)alloc(BB*HH*4);
  float* c0        = (float*)alloc(BB*HH*4);
  float* hn        = (float*)alloc((size_t)(HN_M+1)*BB*HH*4);
  float* ctx       = (float*)alloc((size_t)(CX_M+1)*BB*256*4);
  float* attn      = (float*)alloc((size_t)(AT_M+1)*BB*SS*4);
  float* covloss   = (float*)alloc((size_t)(CV_M+1)*BB*2*4);
  float* pm        = (float*)alloc((size_t)(PM_M+1)*BB*CGB*4);
  float* ps        = (float*)alloc((size_t)(PM_M+1)*BB*CGB*4);
  unsigned* bar    = (unsigned*)alloc(4096);

  // ---- encoder-transient region ----
  float* emb     = (float*)alloc((size_t)BB*SS*DD*4);
  float* Xf      = (float*)alloc(((size_t)BB*SS*G4 + 8*G4)*4);
  float* Xb      = (float*)alloc(((size_t)BB*SS*G4 + 8*G4)*4);
  float* WihT_f  = (float*)alloc((size_t)256*512*4);
  float* WihT_b  = (float*)alloc((size_t)256*512*4);
  unsigned* W2T_f= (unsigned*)alloc((size_t)64*512*4);
  unsigned* W2T_b= (unsigned*)alloc((size_t)64*512*4);
  float* out_f   = (float*)alloc((size_t)BB*SS*HH*4);
  float* out_r   = (float*)alloc((size_t)BB*SS*HH*4);
  float* W1aT    = (float*)alloc((size_t)256*128*4);
  int*   ridx    = (int*)  alloc((size_t)BB*SS*4);

  k_prep_small<<<1569,256,0,stream>>>(Wih_f,Wih_b,Whh_f,Whh_b,W1,Wdhh,
                                      WihT_f,WihT_b,W2T_f,W2T_b,W1aT,W1c,W1h2,Wdh2T);
  k_xd<<<TT,512,0,stream>>>(summary, wv, Wdih, bdih, bdhh, Xd, bar);
  k_embed<<<BB*SS,64,0,stream>>>(text, tlen, wv, emb, ridx);
  k_xgemm<<<512,256,0,stream>>>(emb, ridx, WihT_f, bih_f, bhh_f, Xf, 0);
  k_xgemm<<<512,256,0,stream>>>(emb, ridx, WihT_b, bih_b, bhh_b, Xb, 1);
  k_encoder<<<dim3(8,2),512,0,stream>>>(Xf,Xb,W2T_f,W2T_b,tlen,out_f,out_r,h0,c0);
  k_post<<<dim3(8,16),256,0,stream>>>(out_f,out_r,ridx,W1aT,ts_h,TS1Th);

  PArgs a;
  a.summary=summary; a.slen=slen;
  a.Xd=Xd; a.TS1Th=TS1Th; a.ts_h=ts_h;
  a.W1h2g=W1h2; a.W1c=W1c; a.W2=W2; a.b1=b1;
  a.Wdh2T=Wdh2T; a.Wl=Wl; a.bl=bl;
  a.h0=h0; a.c0=c0;
  a.hn=hn; a.ctx=ctx; a.attn=attn; a.covloss=covloss;
  a.pm=pm; a.ps=ps; a.bar=bar; a.out=(float*)d_out;

  k_decode<<<NBLK,512,0,stream>>>(a);
}